// Round 1
// baseline (1067.451 us; speedup 1.0000x reference)
//
#include <hip/hip_runtime.h>
#include <math.h>

#define N_NODES 50000
#define N_EDGES 800000
#define IN_F 128
#define H_F 256
#define OUT_F 10
#define N_G 128

// ------------------------------------------------------------------
// CSR build: histogram of edge destinations, scan, placement.
// ------------------------------------------------------------------
__global__ void count_edges_kernel(const int* __restrict__ col,
                                   int* __restrict__ counts, int E) {
    int e = blockIdx.x * blockDim.x + threadIdx.x;
    if (e < E) atomicAdd(&counts[col[e]], 1);
}

__global__ void dinv_kernel(const int* __restrict__ counts,
                            float* __restrict__ dinv, int n) {
    int i = blockIdx.x * blockDim.x + threadIdx.x;
    if (i < n) dinv[i] = rsqrtf((float)(counts[i] + 1));
}

// Single-block exclusive scan over n ints (wave shuffle scan + wave-sum scan).
__global__ __launch_bounds__(1024) void scan_kernel(const int* __restrict__ counts,
                                                    int* __restrict__ offsets, int n) {
    __shared__ int wsum[16];
    __shared__ int wpre[16];
    __shared__ int total;
    __shared__ int running;
    int tid = threadIdx.x;
    int lane = tid & 63;
    int wid = tid >> 6;
    if (tid == 0) running = 0;
    __syncthreads();
    for (int base = 0; base < n; base += 1024) {
        int i = base + tid;
        int v = (i < n) ? counts[i] : 0;
        int x = v;
        #pragma unroll
        for (int off = 1; off < 64; off <<= 1) {
            int t = __shfl_up(x, off);
            if (lane >= off) x += t;
        }
        if (lane == 63) wsum[wid] = x;
        __syncthreads();
        if (tid == 0) {
            int s = 0;
            #pragma unroll
            for (int w = 0; w < 16; ++w) { wpre[w] = s; s += wsum[w]; }
            total = s;
        }
        __syncthreads();
        if (i < n) offsets[i] = running + wpre[wid] + x - v;   // exclusive
        __syncthreads();
        if (tid == 0) running += total;
        __syncthreads();
    }
    if (threadIdx.x == 0) offsets[n] = running;
}

__global__ void fill_csr_kernel(const int* __restrict__ row, const int* __restrict__ col,
                                const int* __restrict__ offsets, int* __restrict__ cursor,
                                int* __restrict__ csr_row, int E) {
    int e = blockIdx.x * blockDim.x + threadIdx.x;
    if (e < E) {
        int c = col[e];
        int p = atomicAdd(&cursor[c], 1);
        csr_row[offsets[c] + p] = row[e];
    }
}

// batch is sorted: gstart[g] = first node index of graph g; gstart[G] = N.
__global__ void graph_starts_kernel(const int* __restrict__ batch,
                                    int* __restrict__ gstart, int n, int G) {
    int i = blockIdx.x * blockDim.x + threadIdx.x;
    if (i >= n) return;
    int b = batch[i];
    if (i == 0) {
        for (int g = 0; g <= b; ++g) gstart[g] = 0;
    } else {
        int p = batch[i - 1];
        if (p != b) { for (int g = p + 1; g <= b; ++g) gstart[g] = i; }
    }
    if (i == n - 1) {
        for (int g = b + 1; g <= G; ++g) gstart[g] = n;
    }
}

// ------------------------------------------------------------------
// fp32 tiled GEMM: C[n x 256] = A[n x K] @ B[K x 256]
// 64x64 tile per 256-thread block, 4x4 per thread, BK=16.
// ------------------------------------------------------------------
#define BM 64
#define BN 64
#define BK 16

__global__ __launch_bounds__(256) void gemm_kernel(const float* __restrict__ A,
                                                   const float* __restrict__ B,
                                                   float* __restrict__ C,
                                                   int n, int K) {
    __shared__ float As[BK][BM + 4];   // stride 68 floats = 272 B (16B-aligned rows)
    __shared__ float Bs[BK][BN];
    int tid = threadIdx.x;
    int tx = tid & 15;
    int ty = tid >> 4;
    int row0 = blockIdx.x * BM;
    int col0 = blockIdx.y * BN;
    float acc[4][4] = {};
    int lrA = tid >> 2;          // 0..63 : A tile row
    int lkA = (tid & 3) << 2;    // 0,4,8,12 : A tile k (float4)
    int lkB = tid >> 4;          // 0..15 : B tile k
    int lcB = (tid & 15) << 2;   // 0..60 : B tile col (float4)
    for (int k0 = 0; k0 < K; k0 += BK) {
        float4 a;
        int gr = row0 + lrA;
        if (gr < n) a = *(const float4*)&A[(size_t)gr * K + k0 + lkA];
        else        a = make_float4(0.f, 0.f, 0.f, 0.f);
        As[lkA + 0][lrA] = a.x; As[lkA + 1][lrA] = a.y;
        As[lkA + 2][lrA] = a.z; As[lkA + 3][lrA] = a.w;
        float4 b = *(const float4*)&B[(size_t)(k0 + lkB) * H_F + col0 + lcB];
        *(float4*)&Bs[lkB][lcB] = b;
        __syncthreads();
        #pragma unroll
        for (int k = 0; k < BK; ++k) {
            float4 av = *(const float4*)&As[k][ty << 2];
            float4 bv = *(const float4*)&Bs[k][tx << 2];
            float a4[4] = {av.x, av.y, av.z, av.w};
            float b4[4] = {bv.x, bv.y, bv.z, bv.w};
            #pragma unroll
            for (int i = 0; i < 4; ++i)
                #pragma unroll
                for (int j = 0; j < 4; ++j)
                    acc[i][j] += a4[i] * b4[j];
        }
        __syncthreads();
    }
    #pragma unroll
    for (int i = 0; i < 4; ++i) {
        int gr = row0 + (ty << 2) + i;
        if (gr < n) {
            float4 v = make_float4(acc[i][0], acc[i][1], acc[i][2], acc[i][3]);
            *(float4*)&C[(size_t)gr * H_F + col0 + (tx << 2)] = v;
        }
    }
}

// ------------------------------------------------------------------
// GCN aggregation (gather form, no atomics) + ReLU:
// hout[i] = relu( dinv[i]^2 * hw[i] + sum_{e: col=i} dinv[i]*dinv[row_e]*hw[row_e] )
// One block per node, one channel per thread.
// ------------------------------------------------------------------
__global__ __launch_bounds__(256) void aggregate_kernel(const float* __restrict__ hw,
                                                        const float* __restrict__ dinv,
                                                        const int* __restrict__ offsets,
                                                        const int* __restrict__ csr_row,
                                                        float* __restrict__ hout) {
    int i = blockIdx.x;
    int c = threadIdx.x;
    float di = dinv[i];
    float acc = di * di * hw[(size_t)i * H_F + c];
    int s = offsets[i], e = offsets[i + 1];
    for (int t = s; t < e; ++t) {
        int r = csr_row[t];                 // uniform across wave -> broadcast
        acc += di * dinv[r] * hw[(size_t)r * H_F + c];
    }
    hout[(size_t)i * H_F + c] = fmaxf(acc, 0.0f);
}

// ------------------------------------------------------------------
// Global mean pool using sorted-batch ranges.
// ------------------------------------------------------------------
__global__ __launch_bounds__(256) void pool_kernel(const float* __restrict__ h,
                                                   const int* __restrict__ gstart,
                                                   float* __restrict__ pooled) {
    int g = blockIdx.x, c = threadIdx.x;
    int s = gstart[g], e = gstart[g + 1];
    float sum = 0.f;
    for (int i = s; i < e; ++i) sum += h[(size_t)i * H_F + c];
    int cnt = e - s;
    pooled[g * H_F + c] = sum / (float)max(cnt, 1);
}

__global__ __launch_bounds__(256) void mlp1_kernel(const float* __restrict__ pooled,
                                                   const float* __restrict__ Wm1,
                                                   const float* __restrict__ bm1,
                                                   float* __restrict__ hmid) {
    __shared__ float p[H_F];
    int g = blockIdx.x, j = threadIdx.x;
    p[j] = pooled[g * H_F + j];
    __syncthreads();
    float acc = bm1[j];
    for (int k = 0; k < H_F; ++k) acc += p[k] * Wm1[k * H_F + j];
    hmid[g * H_F + j] = fmaxf(acc, 0.f);
}

// last = hmid @ Wm2 + bm2; outputs: log_softmax(last), sigmoid(last), last.
__global__ __launch_bounds__(64) void head_kernel(const float* __restrict__ hmid,
                                                  const float* __restrict__ Wm2,
                                                  const float* __restrict__ bm2,
                                                  float* __restrict__ out) {
    __shared__ float hrow[H_F];
    __shared__ float lastv[OUT_F];
    __shared__ float stats[2];
    int g = blockIdx.x, t = threadIdx.x;
    for (int k = t; k < H_F; k += 64) hrow[k] = hmid[g * H_F + k];
    __syncthreads();
    if (t < OUT_F) {
        float acc = bm2[t];
        for (int k = 0; k < H_F; ++k) acc += hrow[k] * Wm2[k * OUT_F + t];
        lastv[t] = acc;
    }
    __syncthreads();
    if (t == 0) {
        float m = -1e30f;
        for (int o = 0; o < OUT_F; ++o) m = fmaxf(m, lastv[o]);
        float s = 0.f;
        for (int o = 0; o < OUT_F; ++o) s += expf(lastv[o] - m);
        stats[0] = m; stats[1] = logf(s);
    }
    __syncthreads();
    if (t < OUT_F) {
        float v = lastv[t];
        out[g * OUT_F + t] = v - stats[0] - stats[1];
        out[(size_t)N_G * OUT_F + g * OUT_F + t] = 1.f / (1.f + expf(-v));
        out[(size_t)2 * N_G * OUT_F + g * OUT_F + t] = v;
    }
}

// ------------------------------------------------------------------
extern "C" void kernel_launch(void* const* d_in, const int* in_sizes, int n_in,
                              void* d_out, int out_size, void* d_ws, size_t ws_size,
                              hipStream_t stream) {
    const float* x   = (const float*)d_in[0];
    const int* edge_index = (const int*)d_in[1];
    // d_in[2] edge_weight: unused by reference
    const int* batch = (const int*)d_in[3];
    const float* W0  = (const float*)d_in[4];
    const float* W1  = (const float*)d_in[5];
    const float* W2  = (const float*)d_in[6];
    const float* Wm1 = (const float*)d_in[7];
    const float* bm1 = (const float*)d_in[8];
    const float* Wm2 = (const float*)d_in[9];
    const float* bm2 = (const float*)d_in[10];
    float* out = (float*)d_out;

    char* ws = (char*)d_ws;
    size_t off = 0;
    auto alloc = [&](size_t bytes) -> void* {
        void* p = ws + off; off += (bytes + 255) & ~(size_t)255; return p;
    };
    float* bufA    = (float*)alloc((size_t)N_NODES * H_F * 4);
    float* bufB    = (float*)alloc((size_t)N_NODES * H_F * 4);
    float* dinv    = (float*)alloc((size_t)N_NODES * 4);
    int*   counts  = (int*)alloc((size_t)N_NODES * 4);
    int*   offsets = (int*)alloc((size_t)(N_NODES + 1) * 4);
    int*   cursor  = (int*)alloc((size_t)N_NODES * 4);
    int*   csr_row = (int*)alloc((size_t)N_EDGES * 4);
    int*   gstart  = (int*)alloc((size_t)(N_G + 1) * 4);
    float* pooled  = (float*)alloc((size_t)N_G * H_F * 4);
    float* hmid    = (float*)alloc((size_t)N_G * H_F * 4);

    const int* row = edge_index;              // edge_index[0][:]
    const int* col = edge_index + N_EDGES;    // edge_index[1][:]

    hipMemsetAsync(counts, 0, (size_t)N_NODES * 4, stream);
    hipMemsetAsync(cursor, 0, (size_t)N_NODES * 4, stream);

    count_edges_kernel<<<(N_EDGES + 255) / 256, 256, 0, stream>>>(col, counts, N_EDGES);
    dinv_kernel<<<(N_NODES + 255) / 256, 256, 0, stream>>>(counts, dinv, N_NODES);
    scan_kernel<<<1, 1024, 0, stream>>>(counts, offsets, N_NODES);
    fill_csr_kernel<<<(N_EDGES + 255) / 256, 256, 0, stream>>>(row, col, offsets, cursor,
                                                               csr_row, N_EDGES);
    graph_starts_kernel<<<(N_NODES + 255) / 256, 256, 0, stream>>>(batch, gstart, N_NODES, N_G);

    dim3 gg((N_NODES + BM - 1) / BM, H_F / BN);
    // layer 0
    gemm_kernel<<<gg, 256, 0, stream>>>(x, W0, bufA, N_NODES, IN_F);
    aggregate_kernel<<<N_NODES, 256, 0, stream>>>(bufA, dinv, offsets, csr_row, bufB);
    // layer 1
    gemm_kernel<<<gg, 256, 0, stream>>>(bufB, W1, bufA, N_NODES, H_F);
    aggregate_kernel<<<N_NODES, 256, 0, stream>>>(bufA, dinv, offsets, csr_row, bufB);
    // layer 2
    gemm_kernel<<<gg, 256, 0, stream>>>(bufB, W2, bufA, N_NODES, H_F);
    aggregate_kernel<<<N_NODES, 256, 0, stream>>>(bufA, dinv, offsets, csr_row, bufB);

    pool_kernel<<<N_G, H_F, 0, stream>>>(bufB, gstart, pooled);
    mlp1_kernel<<<N_G, H_F, 0, stream>>>(pooled, Wm1, bm1, hmid);
    head_kernel<<<N_G, 64, 0, stream>>>(hmid, Wm2, bm2, out);
}

// Round 2
// 741.005 us; speedup vs baseline: 1.4405x; 1.4405x over previous
//
#include <hip/hip_runtime.h>
#include <math.h>

#define N_NODES 50000
#define N_PAD   50048          // padded to multiple of 128 for GEMM tiles
#define N_EDGES 800000
#define IN_F 128
#define H_F 256
#define OUT_F 10
#define N_G 128

typedef __attribute__((ext_vector_type(8))) short bf16x8;
typedef __attribute__((ext_vector_type(4))) float f32x4;

__device__ inline float bf2f(ushort u) {
    union { unsigned int u; float f; } v; v.u = ((unsigned int)u) << 16; return v.f;
}
__device__ inline ushort f2bf(float x) {
    union { float f; unsigned int u; } v; v.f = x;
    unsigned int r = v.u + 0x7fff + ((v.u >> 16) & 1);
    return (ushort)(r >> 16);
}

// ------------------------------------------------------------------
// CSR build
// ------------------------------------------------------------------
__global__ void count_edges_kernel(const int* __restrict__ col,
                                   int* __restrict__ counts, int E) {
    int e = blockIdx.x * blockDim.x + threadIdx.x;
    if (e < E) atomicAdd(&counts[col[e]], 1);
}

__global__ void dinv_kernel(const int* __restrict__ counts,
                            float* __restrict__ dinv, int n) {
    int i = blockIdx.x * blockDim.x + threadIdx.x;
    if (i < n) dinv[i] = rsqrtf((float)(counts[i] + 1));
}

// chunked scan: (1) per-256-chunk reduce, (2) serial scan of chunk sums,
// (3) per-chunk shuffle scan + chunk offset
__global__ __launch_bounds__(256) void chunk_reduce(const int* __restrict__ counts,
                                                    int* __restrict__ csum, int n) {
    int i = blockIdx.x * 256 + threadIdx.x;
    int v = (i < n) ? counts[i] : 0;
    #pragma unroll
    for (int off = 32; off; off >>= 1) v += __shfl_down(v, off);
    __shared__ int ws[4];
    if ((threadIdx.x & 63) == 0) ws[threadIdx.x >> 6] = v;
    __syncthreads();
    if (threadIdx.x == 0) csum[blockIdx.x] = ws[0] + ws[1] + ws[2] + ws[3];
}

__global__ void scan_chunks(int* __restrict__ csum, int nchunks) {
    if (blockIdx.x == 0 && threadIdx.x == 0) {
        int run = 0;
        for (int c = 0; c < nchunks; ++c) { int v = csum[c]; csum[c] = run; run += v; }
        csum[nchunks] = run;
    }
}

__global__ __launch_bounds__(256) void chunk_scan(const int* __restrict__ counts,
                                                  const int* __restrict__ csum,
                                                  int* __restrict__ offsets,
                                                  int n, int nchunks) {
    int tid = threadIdx.x;
    int i = blockIdx.x * 256 + tid;
    int v = (i < n) ? counts[i] : 0;
    int lane = tid & 63, wid = tid >> 6;
    int x = v;
    #pragma unroll
    for (int off = 1; off < 64; off <<= 1) {
        int t = __shfl_up(x, off);
        if (lane >= off) x += t;
    }
    __shared__ int wsum[4], wpre[4];
    if (lane == 63) wsum[wid] = x;
    __syncthreads();
    if (tid == 0) { int s = 0; for (int k = 0; k < 4; ++k) { wpre[k] = s; s += wsum[k]; } }
    __syncthreads();
    if (i < n) offsets[i] = csum[blockIdx.x] + wpre[wid] + x - v;  // exclusive
    if (blockIdx.x == 0 && tid == 0) offsets[n] = csum[nchunks];
}

__global__ void fill_csr_kernel(const int* __restrict__ row, const int* __restrict__ col,
                                const int* __restrict__ offsets, int* __restrict__ cursor,
                                int* __restrict__ csr_row, int E) {
    int e = blockIdx.x * blockDim.x + threadIdx.x;
    if (e < E) {
        int c = col[e];
        int p = atomicAdd(&cursor[c], 1);
        csr_row[offsets[c] + p] = row[e];
    }
}

__global__ void graph_starts_kernel(const int* __restrict__ batch,
                                    int* __restrict__ gstart, int n, int G) {
    int i = blockIdx.x * blockDim.x + threadIdx.x;
    if (i >= n) return;
    int b = batch[i];
    if (i == 0) {
        for (int g = 0; g <= b; ++g) gstart[g] = 0;
    } else {
        int p = batch[i - 1];
        if (p != b) { for (int g = p + 1; g <= b; ++g) gstart[g] = i; }
    }
    if (i == n - 1) {
        for (int g = b + 1; g <= G; ++g) gstart[g] = n;
    }
}

// ------------------------------------------------------------------
// dtype conversion helpers (once per launch)
// ------------------------------------------------------------------
__global__ void convert_f32_bf16(const float* __restrict__ in, ushort* __restrict__ out,
                                 int n4) {   // n4 = n/4
    int i = blockIdx.x * blockDim.x + threadIdx.x;
    if (i < n4) {
        float4 v = *(const float4*)(in + (size_t)i * 4);
        ushort4 o;
        o.x = f2bf(v.x); o.y = f2bf(v.y); o.z = f2bf(v.z); o.w = f2bf(v.w);
        *(ushort4*)(out + (size_t)i * 4) = o;
    }
}

// W [K][Nc] fp32 row-major -> Wt [Nc][K] bf16 row-major
__global__ void transpose_w_kernel(const float* __restrict__ W, ushort* __restrict__ Wt,
                                   int K, int Nc) {
    int idx = blockIdx.x * blockDim.x + threadIdx.x;
    if (idx < K * Nc) {
        int k = idx / Nc, nn = idx - k * Nc;
        Wt[nn * K + k] = f2bf(W[idx]);
    }
}

// ------------------------------------------------------------------
// bf16 MFMA GEMM: C[N_PAD x 256] = A[N_PAD x K] @ Bt^T   (Bt is [256][K])
// 128x128 tile / block (256 thr, 4 waves in 2x2), BK=32, 16x16x32 MFMA.
// ------------------------------------------------------------------
__global__ __launch_bounds__(256) void gemm_mfma(const ushort* __restrict__ A,
                                                 const ushort* __restrict__ Bt,
                                                 ushort* __restrict__ C,
                                                 int n, int K) {
    __shared__ ushort As[128 * 32];
    __shared__ ushort Bs[128 * 32];
    int tid = threadIdx.x;
    int lane = tid & 63;
    int w = tid >> 6;
    int wm = w & 1, wn = w >> 1;
    int l16 = lane & 15, quad = lane >> 4;
    int row0 = blockIdx.x * 128;
    int col0 = blockIdx.y * 128;
    f32x4 acc[4][4] = {};

    int ar = tid >> 2;              // 0..63 (tile row this thread stages)
    int ak = (tid & 3) * 8;         // bf16 k-offset (16B granule)
    const ushort* Ag = A + (size_t)(row0 + ar) * K + ak;
    const ushort* Bg = Bt + (size_t)(col0 + ar) * K + ak;
    ushort* AsW = As + tid * 8;     // byte addr 16*tid: linear == [row][k] layout
    ushort* BsW = Bs + tid * 8;

    for (int k0 = 0; k0 < K; k0 += 32) {
        uint4 a0 = *(const uint4*)(Ag + k0);
        uint4 a1 = *(const uint4*)(Ag + (size_t)64 * K + k0);
        uint4 b0 = *(const uint4*)(Bg + k0);
        uint4 b1 = *(const uint4*)(Bg + (size_t)64 * K + k0);
        __syncthreads();
        *(uint4*)AsW = a0;
        *(uint4*)(AsW + 64 * 32) = a1;
        *(uint4*)BsW = b0;
        *(uint4*)(BsW + 64 * 32) = b1;
        __syncthreads();
        bf16x8 af[4], bfr[4];
        #pragma unroll
        for (int i = 0; i < 4; ++i)
            af[i] = *(bf16x8*)&As[(wm * 64 + i * 16 + l16) * 32 + quad * 8];
        #pragma unroll
        for (int j = 0; j < 4; ++j)
            bfr[j] = *(bf16x8*)&Bs[(wn * 64 + j * 16 + l16) * 32 + quad * 8];
        #pragma unroll
        for (int i = 0; i < 4; ++i)
            #pragma unroll
            for (int j = 0; j < 4; ++j)
                acc[i][j] = __builtin_amdgcn_mfma_f32_16x16x32_bf16(af[i], bfr[j], acc[i][j], 0, 0, 0);
    }
    // epilogue: C/D layout col=lane&15, row=quad*4+reg
    #pragma unroll
    for (int i = 0; i < 4; ++i) {
        int rowb = row0 + wm * 64 + i * 16 + quad * 4;
        #pragma unroll
        for (int r = 0; r < 4; ++r) {
            int grow = rowb + r;
            if (grow < n) {
                #pragma unroll
                for (int j = 0; j < 4; ++j) {
                    int gcol = col0 + wn * 64 + j * 16 + l16;
                    C[(size_t)grow * H_F + gcol] = f2bf(acc[i][j][r]);
                }
            }
        }
    }
}

// ------------------------------------------------------------------
// GCN aggregation (bf16 gather, fp32 accumulate) + ReLU, bf16 out.
// One wave per node, lane handles 4 channels (8B loads).
// ------------------------------------------------------------------
__global__ __launch_bounds__(256) void aggregate_bf16(const ushort* __restrict__ hw,
                                                      const float* __restrict__ dinv,
                                                      const int* __restrict__ offsets,
                                                      const int* __restrict__ csr_row,
                                                      ushort* __restrict__ hout) {
    int w = threadIdx.x >> 6;
    int lane = threadIdx.x & 63;
    int i = blockIdx.x * 4 + w;
    if (i >= N_NODES) return;
    float di = dinv[i];
    ushort4 sv = *(const ushort4*)(hw + (size_t)i * H_F + lane * 4);
    float s = di * di;
    float a0 = s * bf2f(sv.x), a1 = s * bf2f(sv.y);
    float a2 = s * bf2f(sv.z), a3 = s * bf2f(sv.w);
    int beg = offsets[i], end = offsets[i + 1];
    for (int t = beg; t < end; ++t) {
        int r = csr_row[t];
        float dr = dinv[r];
        ushort4 v = *(const ushort4*)(hw + (size_t)r * H_F + lane * 4);
        float sc = di * dr;
        a0 += sc * bf2f(v.x); a1 += sc * bf2f(v.y);
        a2 += sc * bf2f(v.z); a3 += sc * bf2f(v.w);
    }
    ushort4 o;
    o.x = f2bf(fmaxf(a0, 0.f)); o.y = f2bf(fmaxf(a1, 0.f));
    o.z = f2bf(fmaxf(a2, 0.f)); o.w = f2bf(fmaxf(a3, 0.f));
    *(ushort4*)(hout + (size_t)i * H_F + lane * 4) = o;
}

// ------------------------------------------------------------------
// Pool / MLP head (fp32 math)
// ------------------------------------------------------------------
__global__ __launch_bounds__(256) void pool_kernel(const ushort* __restrict__ h,
                                                   const int* __restrict__ gstart,
                                                   float* __restrict__ pooled) {
    int g = blockIdx.x, c = threadIdx.x;
    int s = gstart[g], e = gstart[g + 1];
    float sum = 0.f;
    for (int i = s; i < e; ++i) sum += bf2f(h[(size_t)i * H_F + c]);
    int cnt = e - s;
    pooled[g * H_F + c] = sum / (float)max(cnt, 1);
}

__global__ __launch_bounds__(256) void mlp1_kernel(const float* __restrict__ pooled,
                                                   const float* __restrict__ Wm1,
                                                   const float* __restrict__ bm1,
                                                   float* __restrict__ hmid) {
    __shared__ float p[H_F];
    int g = blockIdx.x, j = threadIdx.x;
    p[j] = pooled[g * H_F + j];
    __syncthreads();
    float acc = bm1[j];
    for (int k = 0; k < H_F; ++k) acc += p[k] * Wm1[k * H_F + j];
    hmid[g * H_F + j] = fmaxf(acc, 0.f);
}

__global__ __launch_bounds__(64) void head_kernel(const float* __restrict__ hmid,
                                                  const float* __restrict__ Wm2,
                                                  const float* __restrict__ bm2,
                                                  float* __restrict__ out) {
    __shared__ float hrow[H_F];
    __shared__ float lastv[OUT_F];
    __shared__ float stats[2];
    int g = blockIdx.x, t = threadIdx.x;
    for (int k = t; k < H_F; k += 64) hrow[k] = hmid[g * H_F + k];
    __syncthreads();
    if (t < OUT_F) {
        float acc = bm2[t];
        for (int k = 0; k < H_F; ++k) acc += hrow[k] * Wm2[k * OUT_F + t];
        lastv[t] = acc;
    }
    __syncthreads();
    if (t == 0) {
        float m = -1e30f;
        for (int o = 0; o < OUT_F; ++o) m = fmaxf(m, lastv[o]);
        float s = 0.f;
        for (int o = 0; o < OUT_F; ++o) s += expf(lastv[o] - m);
        stats[0] = m; stats[1] = logf(s);
    }
    __syncthreads();
    if (t < OUT_F) {
        float v = lastv[t];
        out[g * OUT_F + t] = v - stats[0] - stats[1];
        out[(size_t)N_G * OUT_F + g * OUT_F + t] = 1.f / (1.f + expf(-v));
        out[(size_t)2 * N_G * OUT_F + g * OUT_F + t] = v;
    }
}

// ------------------------------------------------------------------
extern "C" void kernel_launch(void* const* d_in, const int* in_sizes, int n_in,
                              void* d_out, int out_size, void* d_ws, size_t ws_size,
                              hipStream_t stream) {
    const float* x   = (const float*)d_in[0];
    const int* edge_index = (const int*)d_in[1];
    const int* batch = (const int*)d_in[3];
    const float* W0  = (const float*)d_in[4];
    const float* W1  = (const float*)d_in[5];
    const float* W2  = (const float*)d_in[6];
    const float* Wm1 = (const float*)d_in[7];
    const float* bm1 = (const float*)d_in[8];
    const float* Wm2 = (const float*)d_in[9];
    const float* bm2 = (const float*)d_in[10];
    float* out = (float*)d_out;

    char* ws = (char*)d_ws;
    size_t off = 0;
    auto alloc = [&](size_t bytes) -> void* {
        void* p = ws + off; off += (bytes + 255) & ~(size_t)255; return p;
    };
    ushort* xb     = (ushort*)alloc((size_t)N_PAD * IN_F * 2);
    ushort* bufA   = (ushort*)alloc((size_t)N_PAD * H_F * 2);
    ushort* bufB   = (ushort*)alloc((size_t)N_PAD * H_F * 2);
    ushort* W0t    = (ushort*)alloc((size_t)H_F * IN_F * 2);
    ushort* W1t    = (ushort*)alloc((size_t)H_F * H_F * 2);
    ushort* W2t    = (ushort*)alloc((size_t)H_F * H_F * 2);
    float* dinv    = (float*)alloc((size_t)N_NODES * 4);
    int*   counts  = (int*)alloc((size_t)N_NODES * 4);
    int*   offsets = (int*)alloc((size_t)(N_NODES + 1) * 4);
    int*   cursor  = (int*)alloc((size_t)N_NODES * 4);
    int*   csr_row = (int*)alloc((size_t)N_EDGES * 4);
    int*   csum    = (int*)alloc((size_t)256 * 4);
    int*   gstart  = (int*)alloc((size_t)(N_G + 1) * 4);
    float* pooled  = (float*)alloc((size_t)N_G * H_F * 4);
    float* hmid    = (float*)alloc((size_t)N_G * H_F * 4);

    const int* row = edge_index;
    const int* col = edge_index + N_EDGES;

    hipMemsetAsync(counts, 0, (size_t)N_NODES * 4, stream);
    hipMemsetAsync(cursor, 0, (size_t)N_NODES * 4, stream);

    int nchunks = (N_NODES + 255) / 256;   // 196

    count_edges_kernel<<<(N_EDGES + 255) / 256, 256, 0, stream>>>(col, counts, N_EDGES);
    dinv_kernel<<<(N_NODES + 255) / 256, 256, 0, stream>>>(counts, dinv, N_NODES);
    chunk_reduce<<<nchunks, 256, 0, stream>>>(counts, csum, N_NODES);
    scan_chunks<<<1, 64, 0, stream>>>(csum, nchunks);
    chunk_scan<<<nchunks, 256, 0, stream>>>(counts, csum, offsets, N_NODES, nchunks);
    fill_csr_kernel<<<(N_EDGES + 255) / 256, 256, 0, stream>>>(row, col, offsets, cursor,
                                                               csr_row, N_EDGES);
    graph_starts_kernel<<<(N_NODES + 255) / 256, 256, 0, stream>>>(batch, gstart, N_NODES, N_G);

    // dtype prep
    convert_f32_bf16<<<((N_NODES * IN_F / 4) + 255) / 256, 256, 0, stream>>>(
        x, xb, N_NODES * IN_F / 4);
    transpose_w_kernel<<<(IN_F * H_F + 255) / 256, 256, 0, stream>>>(W0, W0t, IN_F, H_F);
    transpose_w_kernel<<<(H_F * H_F + 255) / 256, 256, 0, stream>>>(W1, W1t, H_F, H_F);
    transpose_w_kernel<<<(H_F * H_F + 255) / 256, 256, 0, stream>>>(W2, W2t, H_F, H_F);

    dim3 gg(N_PAD / 128, H_F / 128);
    int agg_blocks = (N_NODES + 3) / 4;
    // layer 0
    gemm_mfma<<<gg, 256, 0, stream>>>(xb, W0t, bufA, N_NODES, IN_F);
    aggregate_bf16<<<agg_blocks, 256, 0, stream>>>(bufA, dinv, offsets, csr_row, bufB);
    // layer 1
    gemm_mfma<<<gg, 256, 0, stream>>>(bufB, W1t, bufA, N_NODES, H_F);
    aggregate_bf16<<<agg_blocks, 256, 0, stream>>>(bufA, dinv, offsets, csr_row, bufB);
    // layer 2
    gemm_mfma<<<gg, 256, 0, stream>>>(bufB, W2t, bufA, N_NODES, H_F);
    aggregate_bf16<<<agg_blocks, 256, 0, stream>>>(bufA, dinv, offsets, csr_row, bufB);

    pool_kernel<<<N_G, H_F, 0, stream>>>(bufB, gstart, pooled);
    mlp1_kernel<<<N_G, H_F, 0, stream>>>(pooled, Wm1, bm1, hmid);
    head_kernel<<<N_G, 64, 0, stream>>>(hmid, Wm2, bm2, out);
}

// Round 3
// 499.875 us; speedup vs baseline: 2.1354x; 1.4824x over previous
//
#include <hip/hip_runtime.h>
#include <math.h>

#define N_NODES 50000
#define N_PAD   50048          // padded to multiple of 128 for GEMM tiles
#define N_EDGES 800000
#define IN_F 128
#define H_F 256
#define OUT_F 10
#define N_G 128
#define POOL_CHUNK 128
#define POOL_MAXCHUNKS 16

typedef __attribute__((ext_vector_type(8))) short bf16x8;
typedef __attribute__((ext_vector_type(4))) float f32x4;

__device__ inline float bf2f(ushort u) {
    union { unsigned int u; float f; } v; v.u = ((unsigned int)u) << 16; return v.f;
}
__device__ inline ushort f2bf(float x) {
    union { float f; unsigned int u; } v; v.f = x;
    unsigned int r = v.u + 0x7fff + ((v.u >> 16) & 1);
    return (ushort)(r >> 16);
}

// ------------------------------------------------------------------
// CSR build
// ------------------------------------------------------------------
__global__ void count_edges_kernel(const int* __restrict__ col,
                                   int* __restrict__ counts, int E) {
    int e = blockIdx.x * blockDim.x + threadIdx.x;
    if (e < E) atomicAdd(&counts[col[e]], 1);
}

__global__ void dinv_kernel(const int* __restrict__ counts,
                            float* __restrict__ dinv, int n) {
    int i = blockIdx.x * blockDim.x + threadIdx.x;
    if (i < n) dinv[i] = rsqrtf((float)(counts[i] + 1));
}

__global__ __launch_bounds__(256) void chunk_reduce(const int* __restrict__ counts,
                                                    int* __restrict__ csum, int n) {
    int i = blockIdx.x * 256 + threadIdx.x;
    int v = (i < n) ? counts[i] : 0;
    #pragma unroll
    for (int off = 32; off; off >>= 1) v += __shfl_down(v, off);
    __shared__ int ws[4];
    if ((threadIdx.x & 63) == 0) ws[threadIdx.x >> 6] = v;
    __syncthreads();
    if (threadIdx.x == 0) csum[blockIdx.x] = ws[0] + ws[1] + ws[2] + ws[3];
}

__global__ void scan_chunks(int* __restrict__ csum, int nchunks) {
    if (blockIdx.x == 0 && threadIdx.x == 0) {
        int run = 0;
        for (int c = 0; c < nchunks; ++c) { int v = csum[c]; csum[c] = run; run += v; }
        csum[nchunks] = run;
    }
}

__global__ __launch_bounds__(256) void chunk_scan(const int* __restrict__ counts,
                                                  const int* __restrict__ csum,
                                                  int* __restrict__ offsets,
                                                  int n, int nchunks) {
    int tid = threadIdx.x;
    int i = blockIdx.x * 256 + tid;
    int v = (i < n) ? counts[i] : 0;
    int lane = tid & 63, wid = tid >> 6;
    int x = v;
    #pragma unroll
    for (int off = 1; off < 64; off <<= 1) {
        int t = __shfl_up(x, off);
        if (lane >= off) x += t;
    }
    __shared__ int wsum[4], wpre[4];
    if (lane == 63) wsum[wid] = x;
    __syncthreads();
    if (tid == 0) { int s = 0; for (int k = 0; k < 4; ++k) { wpre[k] = s; s += wsum[k]; } }
    __syncthreads();
    if (i < n) offsets[i] = csum[blockIdx.x] + wpre[wid] + x - v;  // exclusive
    if (blockIdx.x == 0 && tid == 0) offsets[n] = csum[nchunks];
}

// CSR with packed (source row, edge weight) — weight = dinv[dst]*dinv[src]
__global__ void fill_csr_kernel(const int* __restrict__ row, const int* __restrict__ col,
                                const int* __restrict__ offsets, int* __restrict__ cursor,
                                const float* __restrict__ dinv,
                                int2* __restrict__ csr_ew, int E) {
    int e = blockIdx.x * blockDim.x + threadIdx.x;
    if (e < E) {
        int c = col[e];
        int r = row[e];
        int p = atomicAdd(&cursor[c], 1);
        float w = dinv[c] * dinv[r];
        csr_ew[offsets[c] + p] = make_int2(r, __float_as_int(w));
    }
}

__global__ void graph_starts_kernel(const int* __restrict__ batch,
                                    int* __restrict__ gstart, int n, int G) {
    int i = blockIdx.x * blockDim.x + threadIdx.x;
    if (i >= n) return;
    int b = batch[i];
    if (i == 0) {
        for (int g = 0; g <= b; ++g) gstart[g] = 0;
    } else {
        int p = batch[i - 1];
        if (p != b) { for (int g = p + 1; g <= b; ++g) gstart[g] = i; }
    }
    if (i == n - 1) {
        for (int g = b + 1; g <= G; ++g) gstart[g] = n;
    }
}

// ------------------------------------------------------------------
// dtype conversion helpers (once per launch)
// ------------------------------------------------------------------
__global__ void convert_f32_bf16(const float* __restrict__ in, ushort* __restrict__ out,
                                 int n4) {
    int i = blockIdx.x * blockDim.x + threadIdx.x;
    if (i < n4) {
        float4 v = *(const float4*)(in + (size_t)i * 4);
        ushort4 o;
        o.x = f2bf(v.x); o.y = f2bf(v.y); o.z = f2bf(v.z); o.w = f2bf(v.w);
        *(ushort4*)(out + (size_t)i * 4) = o;
    }
}

// W [K][Nc] fp32 row-major -> Wt [Nc][K] bf16 row-major
__global__ void transpose_w_kernel(const float* __restrict__ W, ushort* __restrict__ Wt,
                                   int K, int Nc) {
    int idx = blockIdx.x * blockDim.x + threadIdx.x;
    if (idx < K * Nc) {
        int k = idx / Nc, nn = idx - k * Nc;
        Wt[nn * K + k] = f2bf(W[idx]);
    }
}

// ------------------------------------------------------------------
// bf16 MFMA GEMM: C[N_PAD x 256] = A[N_PAD x K] @ Bt^T   (Bt is [256][K])
// ------------------------------------------------------------------
__global__ __launch_bounds__(256) void gemm_mfma(const ushort* __restrict__ A,
                                                 const ushort* __restrict__ Bt,
                                                 ushort* __restrict__ C,
                                                 int n, int K) {
    __shared__ ushort As[128 * 32];
    __shared__ ushort Bs[128 * 32];
    int tid = threadIdx.x;
    int lane = tid & 63;
    int w = tid >> 6;
    int wm = w & 1, wn = w >> 1;
    int l16 = lane & 15, quad = lane >> 4;
    int row0 = blockIdx.x * 128;
    int col0 = blockIdx.y * 128;
    f32x4 acc[4][4] = {};

    int ar = tid >> 2;
    int ak = (tid & 3) * 8;
    const ushort* Ag = A + (size_t)(row0 + ar) * K + ak;
    const ushort* Bg = Bt + (size_t)(col0 + ar) * K + ak;
    ushort* AsW = As + tid * 8;
    ushort* BsW = Bs + tid * 8;

    for (int k0 = 0; k0 < K; k0 += 32) {
        uint4 a0 = *(const uint4*)(Ag + k0);
        uint4 a1 = *(const uint4*)(Ag + (size_t)64 * K + k0);
        uint4 b0 = *(const uint4*)(Bg + k0);
        uint4 b1 = *(const uint4*)(Bg + (size_t)64 * K + k0);
        __syncthreads();
        *(uint4*)AsW = a0;
        *(uint4*)(AsW + 64 * 32) = a1;
        *(uint4*)BsW = b0;
        *(uint4*)(BsW + 64 * 32) = b1;
        __syncthreads();
        bf16x8 af[4], bfr[4];
        #pragma unroll
        for (int i = 0; i < 4; ++i)
            af[i] = *(bf16x8*)&As[(wm * 64 + i * 16 + l16) * 32 + quad * 8];
        #pragma unroll
        for (int j = 0; j < 4; ++j)
            bfr[j] = *(bf16x8*)&Bs[(wn * 64 + j * 16 + l16) * 32 + quad * 8];
        #pragma unroll
        for (int i = 0; i < 4; ++i)
            #pragma unroll
            for (int j = 0; j < 4; ++j)
                acc[i][j] = __builtin_amdgcn_mfma_f32_16x16x32_bf16(af[i], bfr[j], acc[i][j], 0, 0, 0);
    }
    #pragma unroll
    for (int i = 0; i < 4; ++i) {
        int rowb = row0 + wm * 64 + i * 16 + quad * 4;
        #pragma unroll
        for (int r = 0; r < 4; ++r) {
            int grow = rowb + r;
            if (grow < n) {
                #pragma unroll
                for (int j = 0; j < 4; ++j) {
                    int gcol = col0 + wn * 64 + j * 16 + l16;
                    C[(size_t)grow * H_F + gcol] = f2bf(acc[i][j][r]);
                }
            }
        }
    }
}

// ------------------------------------------------------------------
// GCN aggregation: wave per node, lane = 4 channels, edge loop unrolled x4
// for memory-level parallelism. Edge weights precomputed in CSR.
// ------------------------------------------------------------------
__global__ __launch_bounds__(256) void aggregate_bf16(const ushort* __restrict__ hw,
                                                      const float* __restrict__ dinv,
                                                      const int* __restrict__ offsets,
                                                      const int2* __restrict__ csr_ew,
                                                      ushort* __restrict__ hout) {
    int w = threadIdx.x >> 6;
    int lane = threadIdx.x & 63;
    int i = blockIdx.x * 4 + w;
    if (i >= N_NODES) return;
    float di = dinv[i];
    const ushort* base = hw + (size_t)lane * 4;
    ushort4 sv = *(const ushort4*)(base + (size_t)i * H_F);
    float s = di * di;
    float a0 = s * bf2f(sv.x), a1 = s * bf2f(sv.y);
    float a2 = s * bf2f(sv.z), a3 = s * bf2f(sv.w);
    int t = offsets[i], end = offsets[i + 1];
    for (; t + 4 <= end; t += 4) {
        int2 e0 = csr_ew[t + 0];
        int2 e1 = csr_ew[t + 1];
        int2 e2 = csr_ew[t + 2];
        int2 e3 = csr_ew[t + 3];
        ushort4 v0 = *(const ushort4*)(base + (size_t)e0.x * H_F);
        ushort4 v1 = *(const ushort4*)(base + (size_t)e1.x * H_F);
        ushort4 v2 = *(const ushort4*)(base + (size_t)e2.x * H_F);
        ushort4 v3 = *(const ushort4*)(base + (size_t)e3.x * H_F);
        float w0 = __int_as_float(e0.y), w1 = __int_as_float(e1.y);
        float w2 = __int_as_float(e2.y), w3 = __int_as_float(e3.y);
        a0 += w0 * bf2f(v0.x); a1 += w0 * bf2f(v0.y);
        a2 += w0 * bf2f(v0.z); a3 += w0 * bf2f(v0.w);
        a0 += w1 * bf2f(v1.x); a1 += w1 * bf2f(v1.y);
        a2 += w1 * bf2f(v1.z); a3 += w1 * bf2f(v1.w);
        a0 += w2 * bf2f(v2.x); a1 += w2 * bf2f(v2.y);
        a2 += w2 * bf2f(v2.z); a3 += w2 * bf2f(v2.w);
        a0 += w3 * bf2f(v3.x); a1 += w3 * bf2f(v3.y);
        a2 += w3 * bf2f(v3.z); a3 += w3 * bf2f(v3.w);
    }
    for (; t < end; ++t) {
        int2 e0 = csr_ew[t];
        ushort4 v0 = *(const ushort4*)(base + (size_t)e0.x * H_F);
        float w0 = __int_as_float(e0.y);
        a0 += w0 * bf2f(v0.x); a1 += w0 * bf2f(v0.y);
        a2 += w0 * bf2f(v0.z); a3 += w0 * bf2f(v0.w);
    }
    ushort4 o;
    o.x = f2bf(fmaxf(a0, 0.f)); o.y = f2bf(fmaxf(a1, 0.f));
    o.z = f2bf(fmaxf(a2, 0.f)); o.w = f2bf(fmaxf(a3, 0.f));
    *(ushort4*)(hout + (size_t)i * H_F + lane * 4) = o;
}

// ------------------------------------------------------------------
// Pool: (graph, node-chunk) blocks, fp32 atomic partial sums.
// ------------------------------------------------------------------
__global__ __launch_bounds__(256) void pool_part(const ushort* __restrict__ h,
                                                 const int* __restrict__ gstart,
                                                 float* __restrict__ pooled) {
    int g = blockIdx.x;
    int s = gstart[g] + blockIdx.y * POOL_CHUNK;
    int e = min(gstart[g + 1], s + POOL_CHUNK);
    if (s >= e) return;
    int c = threadIdx.x;
    float sum = 0.f;
    for (int i = s; i < e; ++i) sum += bf2f(h[(size_t)i * H_F + c]);
    atomicAdd(&pooled[g * H_F + c], sum);
}

__global__ __launch_bounds__(256) void mlp1_kernel(const float* __restrict__ pooled,
                                                   const int* __restrict__ gstart,
                                                   const float* __restrict__ Wm1,
                                                   const float* __restrict__ bm1,
                                                   float* __restrict__ hmid) {
    __shared__ float p[H_F];
    int g = blockIdx.x, j = threadIdx.x;
    int cnt = gstart[g + 1] - gstart[g];
    p[j] = pooled[g * H_F + j] / (float)max(cnt, 1);
    __syncthreads();
    float acc = bm1[j];
    for (int k = 0; k < H_F; ++k) acc += p[k] * Wm1[k * H_F + j];
    hmid[g * H_F + j] = fmaxf(acc, 0.f);
}

__global__ __launch_bounds__(64) void head_kernel(const float* __restrict__ hmid,
                                                  const float* __restrict__ Wm2,
                                                  const float* __restrict__ bm2,
                                                  float* __restrict__ out) {
    __shared__ float hrow[H_F];
    __shared__ float lastv[OUT_F];
    __shared__ float stats[2];
    int g = blockIdx.x, t = threadIdx.x;
    for (int k = t; k < H_F; k += 64) hrow[k] = hmid[g * H_F + k];
    __syncthreads();
    if (t < OUT_F) {
        float acc = bm2[t];
        for (int k = 0; k < H_F; ++k) acc += hrow[k] * Wm2[k * OUT_F + t];
        lastv[t] = acc;
    }
    __syncthreads();
    if (t == 0) {
        float m = -1e30f;
        for (int o = 0; o < OUT_F; ++o) m = fmaxf(m, lastv[o]);
        float s = 0.f;
        for (int o = 0; o < OUT_F; ++o) s += expf(lastv[o] - m);
        stats[0] = m; stats[1] = logf(s);
    }
    __syncthreads();
    if (t < OUT_F) {
        float v = lastv[t];
        out[g * OUT_F + t] = v - stats[0] - stats[1];
        out[(size_t)N_G * OUT_F + g * OUT_F + t] = 1.f / (1.f + expf(-v));
        out[(size_t)2 * N_G * OUT_F + g * OUT_F + t] = v;
    }
}

// ------------------------------------------------------------------
extern "C" void kernel_launch(void* const* d_in, const int* in_sizes, int n_in,
                              void* d_out, int out_size, void* d_ws, size_t ws_size,
                              hipStream_t stream) {
    const float* x   = (const float*)d_in[0];
    const int* edge_index = (const int*)d_in[1];
    const int* batch = (const int*)d_in[3];
    const float* W0  = (const float*)d_in[4];
    const float* W1  = (const float*)d_in[5];
    const float* W2  = (const float*)d_in[6];
    const float* Wm1 = (const float*)d_in[7];
    const float* bm1 = (const float*)d_in[8];
    const float* Wm2 = (const float*)d_in[9];
    const float* bm2 = (const float*)d_in[10];
    float* out = (float*)d_out;

    char* ws = (char*)d_ws;
    size_t off = 0;
    auto alloc = [&](size_t bytes) -> void* {
        void* p = ws + off; off += (bytes + 255) & ~(size_t)255; return p;
    };
    ushort* xb     = (ushort*)alloc((size_t)N_PAD * IN_F * 2);
    ushort* bufA   = (ushort*)alloc((size_t)N_PAD * H_F * 2);
    ushort* bufB   = (ushort*)alloc((size_t)N_PAD * H_F * 2);
    ushort* W0t    = (ushort*)alloc((size_t)H_F * IN_F * 2);
    ushort* W1t    = (ushort*)alloc((size_t)H_F * H_F * 2);
    ushort* W2t    = (ushort*)alloc((size_t)H_F * H_F * 2);
    float* dinv    = (float*)alloc((size_t)N_NODES * 4);
    int*   counts  = (int*)alloc((size_t)N_NODES * 4);
    int*   offsets = (int*)alloc((size_t)(N_NODES + 1) * 4);
    int*   cursor  = (int*)alloc((size_t)N_NODES * 4);
    int2*  csr_ew  = (int2*)alloc((size_t)N_EDGES * 8);
    int*   csum    = (int*)alloc((size_t)256 * 4);
    int*   gstart  = (int*)alloc((size_t)(N_G + 1) * 4);
    float* pooled  = (float*)alloc((size_t)N_G * H_F * 4);
    float* hmid    = (float*)alloc((size_t)N_G * H_F * 4);

    const int* row = edge_index;
    const int* col = edge_index + N_EDGES;

    hipMemsetAsync(counts, 0, (size_t)N_NODES * 4, stream);
    hipMemsetAsync(cursor, 0, (size_t)N_NODES * 4, stream);
    hipMemsetAsync(pooled, 0, (size_t)N_G * H_F * 4, stream);

    int nchunks = (N_NODES + 255) / 256;

    count_edges_kernel<<<(N_EDGES + 255) / 256, 256, 0, stream>>>(col, counts, N_EDGES);
    dinv_kernel<<<(N_NODES + 255) / 256, 256, 0, stream>>>(counts, dinv, N_NODES);
    chunk_reduce<<<nchunks, 256, 0, stream>>>(counts, csum, N_NODES);
    scan_chunks<<<1, 64, 0, stream>>>(csum, nchunks);
    chunk_scan<<<nchunks, 256, 0, stream>>>(counts, csum, offsets, N_NODES, nchunks);
    fill_csr_kernel<<<(N_EDGES + 255) / 256, 256, 0, stream>>>(row, col, offsets, cursor,
                                                               dinv, csr_ew, N_EDGES);
    graph_starts_kernel<<<(N_NODES + 255) / 256, 256, 0, stream>>>(batch, gstart, N_NODES, N_G);

    convert_f32_bf16<<<((N_NODES * IN_F / 4) + 255) / 256, 256, 0, stream>>>(
        x, xb, N_NODES * IN_F / 4);
    transpose_w_kernel<<<(IN_F * H_F + 255) / 256, 256, 0, stream>>>(W0, W0t, IN_F, H_F);
    transpose_w_kernel<<<(H_F * H_F + 255) / 256, 256, 0, stream>>>(W1, W1t, H_F, H_F);
    transpose_w_kernel<<<(H_F * H_F + 255) / 256, 256, 0, stream>>>(W2, W2t, H_F, H_F);

    dim3 gg(N_PAD / 128, H_F / 128);
    int agg_blocks = (N_NODES + 3) / 4;
    gemm_mfma<<<gg, 256, 0, stream>>>(xb, W0t, bufA, N_NODES, IN_F);
    aggregate_bf16<<<agg_blocks, 256, 0, stream>>>(bufA, dinv, offsets, csr_ew, bufB);
    gemm_mfma<<<gg, 256, 0, stream>>>(bufB, W1t, bufA, N_NODES, H_F);
    aggregate_bf16<<<agg_blocks, 256, 0, stream>>>(bufA, dinv, offsets, csr_ew, bufB);
    gemm_mfma<<<gg, 256, 0, stream>>>(bufB, W2t, bufA, N_NODES, H_F);
    aggregate_bf16<<<agg_blocks, 256, 0, stream>>>(bufA, dinv, offsets, csr_ew, bufB);

    dim3 pg(N_G, POOL_MAXCHUNKS);
    pool_part<<<pg, 256, 0, stream>>>(bufB, gstart, pooled);
    mlp1_kernel<<<N_G, H_F, 0, stream>>>(pooled, gstart, Wm1, bm1, hmid);
    head_kernel<<<N_G, 64, 0, stream>>>(hmid, Wm2, bm2, out);
}

// Round 4
// 492.642 us; speedup vs baseline: 2.1668x; 1.0147x over previous
//
#include <hip/hip_runtime.h>
#include <math.h>

#define N_NODES 50000
#define N_PAD   50048          // padded to multiple of 128 for GEMM tiles
#define N_EDGES 800000
#define IN_F 128
#define H_F 256
#define OUT_F 10
#define N_G 128
#define POOL_CHUNK 128
#define POOL_MAXCHUNKS 16

typedef __attribute__((ext_vector_type(8))) short bf16x8;
typedef __attribute__((ext_vector_type(4))) float f32x4;

__device__ inline float bf2f(ushort u) {
    union { unsigned int u; float f; } v; v.u = ((unsigned int)u) << 16; return v.f;
}
__device__ inline ushort f2bf(float x) {
    union { float f; unsigned int u; } v; v.f = x;
    unsigned int r = v.u + 0x7fff + ((v.u >> 16) & 1);
    return (ushort)(r >> 16);
}

// async global->LDS, 16 B per lane; lds dest = wave-uniform base + lane*16
__device__ inline void gl2lds16(const ushort* g, ushort* l) {
    __builtin_amdgcn_global_load_lds(
        (const __attribute__((address_space(1))) unsigned int*)g,
        (__attribute__((address_space(3))) unsigned int*)l,
        16, 0, 0);
}

// ------------------------------------------------------------------
// CSR build
// ------------------------------------------------------------------
__global__ void count_edges_kernel(const int* __restrict__ col,
                                   int* __restrict__ counts, int E) {
    int e = blockIdx.x * blockDim.x + threadIdx.x;
    if (e < E) atomicAdd(&counts[col[e]], 1);
}

__global__ void dinv_kernel(const int* __restrict__ counts,
                            float* __restrict__ dinv, int n) {
    int i = blockIdx.x * blockDim.x + threadIdx.x;
    if (i < n) dinv[i] = rsqrtf((float)(counts[i] + 1));
}

__global__ __launch_bounds__(256) void chunk_reduce(const int* __restrict__ counts,
                                                    int* __restrict__ csum, int n) {
    int i = blockIdx.x * 256 + threadIdx.x;
    int v = (i < n) ? counts[i] : 0;
    #pragma unroll
    for (int off = 32; off; off >>= 1) v += __shfl_down(v, off);
    __shared__ int ws[4];
    if ((threadIdx.x & 63) == 0) ws[threadIdx.x >> 6] = v;
    __syncthreads();
    if (threadIdx.x == 0) csum[blockIdx.x] = ws[0] + ws[1] + ws[2] + ws[3];
}

__global__ void scan_chunks(int* __restrict__ csum, int nchunks) {
    if (blockIdx.x == 0 && threadIdx.x == 0) {
        int run = 0;
        for (int c = 0; c < nchunks; ++c) { int v = csum[c]; csum[c] = run; run += v; }
        csum[nchunks] = run;
    }
}

__global__ __launch_bounds__(256) void chunk_scan(const int* __restrict__ counts,
                                                  const int* __restrict__ csum,
                                                  int* __restrict__ offsets,
                                                  int n, int nchunks) {
    int tid = threadIdx.x;
    int i = blockIdx.x * 256 + tid;
    int v = (i < n) ? counts[i] : 0;
    int lane = tid & 63, wid = tid >> 6;
    int x = v;
    #pragma unroll
    for (int off = 1; off < 64; off <<= 1) {
        int t = __shfl_up(x, off);
        if (lane >= off) x += t;
    }
    __shared__ int wsum[4], wpre[4];
    if (lane == 63) wsum[wid] = x;
    __syncthreads();
    if (tid == 0) { int s = 0; for (int k = 0; k < 4; ++k) { wpre[k] = s; s += wsum[k]; } }
    __syncthreads();
    if (i < n) offsets[i] = csum[blockIdx.x] + wpre[wid] + x - v;  // exclusive
    if (blockIdx.x == 0 && tid == 0) offsets[n] = csum[nchunks];
}

// CSR with packed (source row, edge weight) — weight = dinv[dst]*dinv[src]
__global__ void fill_csr_kernel(const int* __restrict__ row, const int* __restrict__ col,
                                const int* __restrict__ offsets, int* __restrict__ cursor,
                                const float* __restrict__ dinv,
                                int2* __restrict__ csr_ew, int E) {
    int e = blockIdx.x * blockDim.x + threadIdx.x;
    if (e < E) {
        int c = col[e];
        int r = row[e];
        int p = atomicAdd(&cursor[c], 1);
        float w = dinv[c] * dinv[r];
        csr_ew[offsets[c] + p] = make_int2(r, __float_as_int(w));
    }
}

__global__ void graph_starts_kernel(const int* __restrict__ batch,
                                    int* __restrict__ gstart, int n, int G) {
    int i = blockIdx.x * blockDim.x + threadIdx.x;
    if (i >= n) return;
    int b = batch[i];
    if (i == 0) {
        for (int g = 0; g <= b; ++g) gstart[g] = 0;
    } else {
        int p = batch[i - 1];
        if (p != b) { for (int g = p + 1; g <= b; ++g) gstart[g] = i; }
    }
    if (i == n - 1) {
        for (int g = b + 1; g <= G; ++g) gstart[g] = n;
    }
}

// ------------------------------------------------------------------
// dtype conversion helpers (once per launch)
// ------------------------------------------------------------------
__global__ void convert_f32_bf16(const float* __restrict__ in, ushort* __restrict__ out,
                                 int n4) {
    int i = blockIdx.x * blockDim.x + threadIdx.x;
    if (i < n4) {
        float4 v = *(const float4*)(in + (size_t)i * 4);
        ushort4 o;
        o.x = f2bf(v.x); o.y = f2bf(v.y); o.z = f2bf(v.z); o.w = f2bf(v.w);
        *(ushort4*)(out + (size_t)i * 4) = o;
    }
}

// W [K][Nc] fp32 row-major -> Wt [Nc][K] bf16 row-major
__global__ void transpose_w_kernel(const float* __restrict__ W, ushort* __restrict__ Wt,
                                   int K, int Nc) {
    int idx = blockIdx.x * blockDim.x + threadIdx.x;
    if (idx < K * Nc) {
        int k = idx / Nc, nn = idx - k * Nc;
        Wt[nn * K + k] = f2bf(W[idx]);
    }
}

// ------------------------------------------------------------------
// bf16 MFMA GEMM: C[N_PAD x 256] = A[N_PAD x K] @ Bt^T   (Bt is [256][K])
// 128x128 tile / block (4 waves 2x2), BK=32, async global_load_lds staging.
// ------------------------------------------------------------------
__global__ __launch_bounds__(256) void gemm_mfma(const ushort* __restrict__ A,
                                                 const ushort* __restrict__ Bt,
                                                 ushort* __restrict__ C,
                                                 int n, int K) {
    __shared__ ushort As[128 * 32];
    __shared__ ushort Bs[128 * 32];
    int tid = threadIdx.x;
    int lane = tid & 63;
    int w = tid >> 6;
    int wm = w & 1, wn = w >> 1;
    int l16 = lane & 15, quad = lane >> 4;
    int row0 = blockIdx.x * 128;
    int col0 = blockIdx.y * 128;
    f32x4 acc[4][4] = {};

    // staging map: thread tid covers tile row = tid>>2, k-part = (tid&3)*8.
    // LDS byte dest = tid*16 == [row][32k] linear layout; per wave this is
    // wave-uniform base (w*1024) + lane*16, exactly global_load_lds semantics.
    int ar = tid >> 2;
    int ak = (tid & 3) * 8;
    const ushort* Ag = A + (size_t)(row0 + ar) * K + ak;
    const ushort* Bg = Bt + (size_t)(col0 + ar) * K + ak;
    ushort* AsD0 = As + w * 512;           // rows 0..63   (bytes w*1024)
    ushort* AsD1 = As + 2048 + w * 512;    // rows 64..127 (bytes 4096 + w*1024)
    ushort* BsD0 = Bs + w * 512;
    ushort* BsD1 = Bs + 2048 + w * 512;

    for (int k0 = 0; k0 < K; k0 += 32) {
        __syncthreads();                   // prior iter's ds_reads complete
        gl2lds16(Ag + k0, AsD0);
        gl2lds16(Ag + (size_t)64 * K + k0, AsD1);
        gl2lds16(Bg + k0, BsD0);
        gl2lds16(Bg + (size_t)64 * K + k0, BsD1);
        __syncthreads();                   // drain vmcnt -> LDS ready
        bf16x8 af[4], bfr[4];
        #pragma unroll
        for (int i = 0; i < 4; ++i)
            af[i] = *(bf16x8*)&As[(wm * 64 + i * 16 + l16) * 32 + quad * 8];
        #pragma unroll
        for (int j = 0; j < 4; ++j)
            bfr[j] = *(bf16x8*)&Bs[(wn * 64 + j * 16 + l16) * 32 + quad * 8];
        #pragma unroll
        for (int i = 0; i < 4; ++i)
            #pragma unroll
            for (int j = 0; j < 4; ++j)
                acc[i][j] = __builtin_amdgcn_mfma_f32_16x16x32_bf16(af[i], bfr[j], acc[i][j], 0, 0, 0);
    }
    #pragma unroll
    for (int i = 0; i < 4; ++i) {
        int rowb = row0 + wm * 64 + i * 16 + quad * 4;
        #pragma unroll
        for (int r = 0; r < 4; ++r) {
            int grow = rowb + r;
            if (grow < n) {
                #pragma unroll
                for (int j = 0; j < 4; ++j) {
                    int gcol = col0 + wn * 64 + j * 16 + l16;
                    C[(size_t)grow * H_F + gcol] = f2bf(acc[i][j][r]);
                }
            }
        }
    }
}

// ------------------------------------------------------------------
// GCN aggregation: wave per node, lane = 4 channels, edge loop unrolled x8.
// ------------------------------------------------------------------
__global__ __launch_bounds__(256) void aggregate_bf16(const ushort* __restrict__ hw,
                                                      const float* __restrict__ dinv,
                                                      const int* __restrict__ offsets,
                                                      const int2* __restrict__ csr_ew,
                                                      ushort* __restrict__ hout) {
    int w = threadIdx.x >> 6;
    int lane = threadIdx.x & 63;
    int i = blockIdx.x * 4 + w;
    if (i >= N_NODES) return;
    float di = dinv[i];
    const ushort* base = hw + (size_t)lane * 4;
    ushort4 sv = *(const ushort4*)(base + (size_t)i * H_F);
    float s = di * di;
    float a0 = s * bf2f(sv.x), a1 = s * bf2f(sv.y);
    float a2 = s * bf2f(sv.z), a3 = s * bf2f(sv.w);
    int t = offsets[i], end = offsets[i + 1];
    for (; t + 8 <= end; t += 8) {
        int2 e[8];
        ushort4 v[8];
        #pragma unroll
        for (int u = 0; u < 8; ++u) e[u] = csr_ew[t + u];
        #pragma unroll
        for (int u = 0; u < 8; ++u) v[u] = *(const ushort4*)(base + (size_t)e[u].x * H_F);
        #pragma unroll
        for (int u = 0; u < 8; ++u) {
            float wq = __int_as_float(e[u].y);
            a0 += wq * bf2f(v[u].x); a1 += wq * bf2f(v[u].y);
            a2 += wq * bf2f(v[u].z); a3 += wq * bf2f(v[u].w);
        }
    }
    for (; t + 4 <= end; t += 4) {
        int2 e0 = csr_ew[t + 0], e1 = csr_ew[t + 1];
        int2 e2 = csr_ew[t + 2], e3 = csr_ew[t + 3];
        ushort4 v0 = *(const ushort4*)(base + (size_t)e0.x * H_F);
        ushort4 v1 = *(const ushort4*)(base + (size_t)e1.x * H_F);
        ushort4 v2 = *(const ushort4*)(base + (size_t)e2.x * H_F);
        ushort4 v3 = *(const ushort4*)(base + (size_t)e3.x * H_F);
        float w0 = __int_as_float(e0.y), w1 = __int_as_float(e1.y);
        float w2 = __int_as_float(e2.y), w3 = __int_as_float(e3.y);
        a0 += w0 * bf2f(v0.x); a1 += w0 * bf2f(v0.y);
        a2 += w0 * bf2f(v0.z); a3 += w0 * bf2f(v0.w);
        a0 += w1 * bf2f(v1.x); a1 += w1 * bf2f(v1.y);
        a2 += w1 * bf2f(v1.z); a3 += w1 * bf2f(v1.w);
        a0 += w2 * bf2f(v2.x); a1 += w2 * bf2f(v2.y);
        a2 += w2 * bf2f(v2.z); a3 += w2 * bf2f(v2.w);
        a0 += w3 * bf2f(v3.x); a1 += w3 * bf2f(v3.y);
        a2 += w3 * bf2f(v3.z); a3 += w3 * bf2f(v3.w);
    }
    for (; t < end; ++t) {
        int2 e0 = csr_ew[t];
        ushort4 v0 = *(const ushort4*)(base + (size_t)e0.x * H_F);
        float w0 = __int_as_float(e0.y);
        a0 += w0 * bf2f(v0.x); a1 += w0 * bf2f(v0.y);
        a2 += w0 * bf2f(v0.z); a3 += w0 * bf2f(v0.w);
    }
    ushort4 o;
    o.x = f2bf(fmaxf(a0, 0.f)); o.y = f2bf(fmaxf(a1, 0.f));
    o.z = f2bf(fmaxf(a2, 0.f)); o.w = f2bf(fmaxf(a3, 0.f));
    *(ushort4*)(hout + (size_t)i * H_F + lane * 4) = o;
}

// ------------------------------------------------------------------
// Pool: (graph, node-chunk) blocks, fp32 atomic partial sums.
// ------------------------------------------------------------------
__global__ __launch_bounds__(256) void pool_part(const ushort* __restrict__ h,
                                                 const int* __restrict__ gstart,
                                                 float* __restrict__ pooled) {
    int g = blockIdx.x;
    int s = gstart[g] + blockIdx.y * POOL_CHUNK;
    int e = min(gstart[g + 1], s + POOL_CHUNK);
    if (s >= e) return;
    int c = threadIdx.x;
    float sum = 0.f;
    for (int i = s; i < e; ++i) sum += bf2f(h[(size_t)i * H_F + c]);
    atomicAdd(&pooled[g * H_F + c], sum);
}

__global__ __launch_bounds__(256) void mlp1_kernel(const float* __restrict__ pooled,
                                                   const int* __restrict__ gstart,
                                                   const float* __restrict__ Wm1,
                                                   const float* __restrict__ bm1,
                                                   float* __restrict__ hmid) {
    __shared__ float p[H_F];
    int g = blockIdx.x, j = threadIdx.x;
    int cnt = gstart[g + 1] - gstart[g];
    p[j] = pooled[g * H_F + j] / (float)max(cnt, 1);
    __syncthreads();
    float acc = bm1[j];
    for (int k = 0; k < H_F; ++k) acc += p[k] * Wm1[k * H_F + j];
    hmid[g * H_F + j] = fmaxf(acc, 0.f);
}

__global__ __launch_bounds__(64) void head_kernel(const float* __restrict__ hmid,
                                                  const float* __restrict__ Wm2,
                                                  const float* __restrict__ bm2,
                                                  float* __restrict__ out) {
    __shared__ float hrow[H_F];
    __shared__ float lastv[OUT_F];
    __shared__ float stats[2];
    int g = blockIdx.x, t = threadIdx.x;
    for (int k = t; k < H_F; k += 64) hrow[k] = hmid[g * H_F + k];
    __syncthreads();
    if (t < OUT_F) {
        float acc = bm2[t];
        for (int k = 0; k < H_F; ++k) acc += hrow[k] * Wm2[k * OUT_F + t];
        lastv[t] = acc;
    }
    __syncthreads();
    if (t == 0) {
        float m = -1e30f;
        for (int o = 0; o < OUT_F; ++o) m = fmaxf(m, lastv[o]);
        float s = 0.f;
        for (int o = 0; o < OUT_F; ++o) s += expf(lastv[o] - m);
        stats[0] = m; stats[1] = logf(s);
    }
    __syncthreads();
    if (t < OUT_F) {
        float v = lastv[t];
        out[g * OUT_F + t] = v - stats[0] - stats[1];
        out[(size_t)N_G * OUT_F + g * OUT_F + t] = 1.f / (1.f + expf(-v));
        out[(size_t)2 * N_G * OUT_F + g * OUT_F + t] = v;
    }
}

// ------------------------------------------------------------------
extern "C" void kernel_launch(void* const* d_in, const int* in_sizes, int n_in,
                              void* d_out, int out_size, void* d_ws, size_t ws_size,
                              hipStream_t stream) {
    const float* x   = (const float*)d_in[0];
    const int* edge_index = (const int*)d_in[1];
    const int* batch = (const int*)d_in[3];
    const float* W0  = (const float*)d_in[4];
    const float* W1  = (const float*)d_in[5];
    const float* W2  = (const float*)d_in[6];
    const float* Wm1 = (const float*)d_in[7];
    const float* bm1 = (const float*)d_in[8];
    const float* Wm2 = (const float*)d_in[9];
    const float* bm2 = (const float*)d_in[10];
    float* out = (float*)d_out;

    char* ws = (char*)d_ws;
    size_t off = 0;
    auto alloc = [&](size_t bytes) -> void* {
        void* p = ws + off; off += (bytes + 255) & ~(size_t)255; return p;
    };
    ushort* xb     = (ushort*)alloc((size_t)N_PAD * IN_F * 2);
    ushort* bufA   = (ushort*)alloc((size_t)N_PAD * H_F * 2);
    ushort* bufB   = (ushort*)alloc((size_t)N_PAD * H_F * 2);
    ushort* W0t    = (ushort*)alloc((size_t)H_F * IN_F * 2);
    ushort* W1t    = (ushort*)alloc((size_t)H_F * H_F * 2);
    ushort* W2t    = (ushort*)alloc((size_t)H_F * H_F * 2);
    float* dinv    = (float*)alloc((size_t)N_NODES * 4);
    int*   counts  = (int*)alloc((size_t)N_NODES * 4);
    int*   offsets = (int*)alloc((size_t)(N_NODES + 1) * 4);
    int*   cursor  = (int*)alloc((size_t)N_NODES * 4);
    int2*  csr_ew  = (int2*)alloc((size_t)N_EDGES * 8);
    int*   csum    = (int*)alloc((size_t)256 * 4);
    int*   gstart  = (int*)alloc((size_t)(N_G + 1) * 4);
    float* pooled  = (float*)alloc((size_t)N_G * H_F * 4);
    float* hmid    = (float*)alloc((size_t)N_G * H_F * 4);

    const int* row = edge_index;
    const int* col = edge_index + N_EDGES;

    hipMemsetAsync(counts, 0, (size_t)N_NODES * 4, stream);
    hipMemsetAsync(cursor, 0, (size_t)N_NODES * 4, stream);
    hipMemsetAsync(pooled, 0, (size_t)N_G * H_F * 4, stream);

    int nchunks = (N_NODES + 255) / 256;

    count_edges_kernel<<<(N_EDGES + 255) / 256, 256, 0, stream>>>(col, counts, N_EDGES);
    dinv_kernel<<<(N_NODES + 255) / 256, 256, 0, stream>>>(counts, dinv, N_NODES);
    chunk_reduce<<<nchunks, 256, 0, stream>>>(counts, csum, N_NODES);
    scan_chunks<<<1, 64, 0, stream>>>(csum, nchunks);
    chunk_scan<<<nchunks, 256, 0, stream>>>(counts, csum, offsets, N_NODES, nchunks);
    fill_csr_kernel<<<(N_EDGES + 255) / 256, 256, 0, stream>>>(row, col, offsets, cursor,
                                                               dinv, csr_ew, N_EDGES);
    graph_starts_kernel<<<(N_NODES + 255) / 256, 256, 0, stream>>>(batch, gstart, N_NODES, N_G);

    convert_f32_bf16<<<((N_NODES * IN_F / 4) + 255) / 256, 256, 0, stream>>>(
        x, xb, N_NODES * IN_F / 4);
    transpose_w_kernel<<<(IN_F * H_F + 255) / 256, 256, 0, stream>>>(W0, W0t, IN_F, H_F);
    transpose_w_kernel<<<(H_F * H_F + 255) / 256, 256, 0, stream>>>(W1, W1t, H_F, H_F);
    transpose_w_kernel<<<(H_F * H_F + 255) / 256, 256, 0, stream>>>(W2, W2t, H_F, H_F);

    dim3 gg(N_PAD / 128, H_F / 128);
    int agg_blocks = (N_NODES + 3) / 4;
    gemm_mfma<<<gg, 256, 0, stream>>>(xb, W0t, bufA, N_NODES, IN_F);
    aggregate_bf16<<<agg_blocks, 256, 0, stream>>>(bufA, dinv, offsets, csr_ew, bufB);
    gemm_mfma<<<gg, 256, 0, stream>>>(bufB, W1t, bufA, N_NODES, H_F);
    aggregate_bf16<<<agg_blocks, 256, 0, stream>>>(bufA, dinv, offsets, csr_ew, bufB);
    gemm_mfma<<<gg, 256, 0, stream>>>(bufB, W2t, bufA, N_NODES, H_F);
    aggregate_bf16<<<agg_blocks, 256, 0, stream>>>(bufA, dinv, offsets, csr_ew, bufB);

    dim3 pg(N_G, POOL_MAXCHUNKS);
    pool_part<<<pg, 256, 0, stream>>>(bufB, gstart, pooled);
    mlp1_kernel<<<N_G, H_F, 0, stream>>>(pooled, gstart, Wm1, bm1, hmid);
    head_kernel<<<N_G, 64, 0, stream>>>(hmid, Wm2, bm2, out);
}

// Round 5
// 455.246 us; speedup vs baseline: 2.3448x; 1.0821x over previous
//
#include <hip/hip_runtime.h>
#include <math.h>

#define N_NODES 50000
#define N_PAD   50048          // padded to multiple of 128 for GEMM tiles
#define N_EDGES 800000
#define IN_F 128
#define H_F 256
#define OUT_F 10
#define N_G 128
#define POOL_CHUNK 128
#define POOL_MAXCHUNKS 16
#define NCHUNKS 196            // ceil(N_NODES/256)

typedef __attribute__((ext_vector_type(8))) short bf16x8;
typedef __attribute__((ext_vector_type(4))) float f32x4;

__device__ inline float bf2f(ushort u) {
    union { unsigned int u; float f; } v; v.u = ((unsigned int)u) << 16; return v.f;
}
__device__ inline ushort f2bf(float x) {
    union { float f; unsigned int u; } v; v.f = x;
    unsigned int r = v.u + 0x7fff + ((v.u >> 16) & 1);
    return (ushort)(r >> 16);
}

// async global->LDS, 16 B per lane; lds dest = wave-uniform base + lane*16
__device__ inline void gl2lds16(const ushort* g, ushort* l) {
    __builtin_amdgcn_global_load_lds(
        (const __attribute__((address_space(1))) unsigned int*)g,
        (__attribute__((address_space(3))) unsigned int*)l,
        16, 0, 0);
}

// ------------------------------------------------------------------
// Mega-fused prep: all mutually independent preprocessing in one launch.
// block roles:
//   [0, 3125)            count_edges (atomic histogram of col)
//   [3125, 9375)         x fp32 -> bf16 (float4/ushort4, 1.6M groups)
//   [9375, 9503)         W0 transpose+cast (128x256)
//   [9503, 9759)         W1 transpose+cast (256x256)
//   [9759, 10015)        W2 transpose+cast
//   [10015, 10211)       graph_starts from sorted batch
// ------------------------------------------------------------------
#define PREP_CE   3125
#define PREP_CV   (PREP_CE + 6250)
#define PREP_T0   (PREP_CV + 128)
#define PREP_T1   (PREP_T0 + 256)
#define PREP_T2   (PREP_T1 + 256)
#define PREP_GS   (PREP_T2 + NCHUNKS)

__global__ __launch_bounds__(256) void prep_kernel(
    const int* __restrict__ col, int* __restrict__ counts,
    const float* __restrict__ x, ushort* __restrict__ xb,
    const float* __restrict__ W0, ushort* __restrict__ W0t,
    const float* __restrict__ W1, ushort* __restrict__ W1t,
    const float* __restrict__ W2, ushort* __restrict__ W2t,
    const int* __restrict__ batch, int* __restrict__ gstart) {
    int b = blockIdx.x;
    int tid = threadIdx.x;
    if (b < PREP_CE) {
        int e = b * 256 + tid;
        if (e < N_EDGES) atomicAdd(&counts[col[e]], 1);
    } else if (b < PREP_CV) {
        int i = (b - PREP_CE) * 256 + tid;      // < 1,600,000 exactly
        float4 v = *(const float4*)(x + (size_t)i * 4);
        ushort4 o;
        o.x = f2bf(v.x); o.y = f2bf(v.y); o.z = f2bf(v.z); o.w = f2bf(v.w);
        *(ushort4*)(xb + (size_t)i * 4) = o;
    } else if (b < PREP_T0) {
        int idx = (b - PREP_CV) * 256 + tid;    // < 32768
        int k = idx >> 8, nn = idx & 255;       // K=128, Nc=256
        W0t[nn * IN_F + k] = f2bf(W0[idx]);
    } else if (b < PREP_T1) {
        int idx = (b - PREP_T0) * 256 + tid;    // < 65536
        int k = idx >> 8, nn = idx & 255;
        W1t[nn * H_F + k] = f2bf(W1[idx]);
    } else if (b < PREP_T2) {
        int idx = (b - PREP_T1) * 256 + tid;
        int k = idx >> 8, nn = idx & 255;
        W2t[nn * H_F + k] = f2bf(W2[idx]);
    } else {
        int i = (b - PREP_T2) * 256 + tid;
        if (i >= N_NODES) return;
        int bb = batch[i];
        if (i == 0) {
            for (int g = 0; g <= bb; ++g) gstart[g] = 0;
        } else {
            int p = batch[i - 1];
            if (p != bb) { for (int g = p + 1; g <= bb; ++g) gstart[g] = i; }
        }
        if (i == N_NODES - 1) {
            for (int g = bb + 1; g <= N_G; ++g) gstart[g] = N_NODES;
        }
    }
}

// ------------------------------------------------------------------
// per-chunk sums of counts (196 blocks)
// ------------------------------------------------------------------
__global__ __launch_bounds__(256) void chunk_reduce(const int* __restrict__ counts,
                                                    int* __restrict__ csum, int n) {
    int i = blockIdx.x * 256 + threadIdx.x;
    int v = (i < n) ? counts[i] : 0;
    #pragma unroll
    for (int off = 32; off; off >>= 1) v += __shfl_down(v, off);
    __shared__ int ws[4];
    if ((threadIdx.x & 63) == 0) ws[threadIdx.x >> 6] = v;
    __syncthreads();
    if (threadIdx.x == 0) csum[blockIdx.x] = ws[0] + ws[1] + ws[2] + ws[3];
}

// ------------------------------------------------------------------
// scan + dinv + cursor-zero, fully parallel (196 blocks):
// each block scans csum[0..195] itself (256-wide shuffle scan) to get its
// chunk base, then scans its own 256 counts, emits exclusive offsets,
// dinv = rsqrt(deg+1), cursor = 0.
// ------------------------------------------------------------------
__global__ __launch_bounds__(256) void scan_dinv_kernel(const int* __restrict__ counts,
                                                        const int* __restrict__ csum,
                                                        int* __restrict__ offsets,
                                                        float* __restrict__ dinv,
                                                        int* __restrict__ cursor, int n) {
    int tid = threadIdx.x;
    int lane = tid & 63, wid = tid >> 6;
    // --- scan csum (196 padded to 256) ---
    int cv = (tid < NCHUNKS) ? csum[tid] : 0;
    int xc = cv;
    #pragma unroll
    for (int off = 1; off < 64; off <<= 1) {
        int t = __shfl_up(xc, off);
        if (lane >= off) xc += t;
    }
    __shared__ int cw[4], cpre[4];
    __shared__ int cexcl[256];
    if (lane == 63) cw[wid] = xc;
    __syncthreads();
    if (tid == 0) { int s = 0; for (int k = 0; k < 4; ++k) { cpre[k] = s; s += cw[k]; } }
    __syncthreads();
    cexcl[tid] = cpre[wid] + xc - cv;
    __syncthreads();
    int base = cexcl[blockIdx.x];
    // --- scan this chunk's counts ---
    int i = blockIdx.x * 256 + tid;
    int v = (i < n) ? counts[i] : 0;
    int x = v;
    #pragma unroll
    for (int off = 1; off < 64; off <<= 1) {
        int t = __shfl_up(x, off);
        if (lane >= off) x += t;
    }
    __shared__ int wsum[4], wpre[4];
    if (lane == 63) wsum[wid] = x;
    __syncthreads();
    if (tid == 0) { int s = 0; for (int k = 0; k < 4; ++k) { wpre[k] = s; s += wsum[k]; } }
    __syncthreads();
    if (i < n) {
        offsets[i] = base + wpre[wid] + x - v;   // exclusive
        dinv[i] = rsqrtf((float)(v + 1));
        cursor[i] = 0;
    }
    if (blockIdx.x == 0 && tid == 0) offsets[n] = N_EDGES;
}

// CSR with packed (source row, edge weight) — weight = dinv[dst]*dinv[src]
__global__ void fill_csr_kernel(const int* __restrict__ row, const int* __restrict__ col,
                                const int* __restrict__ offsets, int* __restrict__ cursor,
                                const float* __restrict__ dinv,
                                int2* __restrict__ csr_ew, int E) {
    int e = blockIdx.x * blockDim.x + threadIdx.x;
    if (e < E) {
        int c = col[e];
        int r = row[e];
        int p = atomicAdd(&cursor[c], 1);
        float w = dinv[c] * dinv[r];
        csr_ew[offsets[c] + p] = make_int2(r, __float_as_int(w));
    }
}

// ------------------------------------------------------------------
// bf16 MFMA GEMM: C[N_PAD x 256] = A[N_PAD x K] @ Bt^T   (Bt is [256][K])
// 128x128 tile / block (4 waves 2x2), BK=32, async global_load_lds staging.
// K is compile-time -> fully unrolled K-loop, constant-folded addresses.
// ------------------------------------------------------------------
template <int K>
__global__ __launch_bounds__(256) void gemm_mfma(const ushort* __restrict__ A,
                                                 const ushort* __restrict__ Bt,
                                                 ushort* __restrict__ C,
                                                 int n) {
    __shared__ ushort As[128 * 32];
    __shared__ ushort Bs[128 * 32];
    int tid = threadIdx.x;
    int lane = tid & 63;
    int w = tid >> 6;
    int wm = w & 1, wn = w >> 1;
    int l16 = lane & 15, quad = lane >> 4;
    int row0 = blockIdx.x * 128;
    int col0 = blockIdx.y * 128;
    f32x4 acc[4][4] = {};

    int ar = tid >> 2;
    int ak = (tid & 3) * 8;
    const ushort* Ag = A + (size_t)(row0 + ar) * K + ak;
    const ushort* Bg = Bt + (size_t)(col0 + ar) * K + ak;
    ushort* AsD0 = As + w * 512;
    ushort* AsD1 = As + 2048 + w * 512;
    ushort* BsD0 = Bs + w * 512;
    ushort* BsD1 = Bs + 2048 + w * 512;

    #pragma unroll
    for (int k0 = 0; k0 < K; k0 += 32) {
        __syncthreads();
        gl2lds16(Ag + k0, AsD0);
        gl2lds16(Ag + (size_t)64 * K + k0, AsD1);
        gl2lds16(Bg + k0, BsD0);
        gl2lds16(Bg + (size_t)64 * K + k0, BsD1);
        __syncthreads();
        bf16x8 af[4], bfr[4];
        #pragma unroll
        for (int i = 0; i < 4; ++i)
            af[i] = *(bf16x8*)&As[(wm * 64 + i * 16 + l16) * 32 + quad * 8];
        #pragma unroll
        for (int j = 0; j < 4; ++j)
            bfr[j] = *(bf16x8*)&Bs[(wn * 64 + j * 16 + l16) * 32 + quad * 8];
        #pragma unroll
        for (int i = 0; i < 4; ++i)
            #pragma unroll
            for (int j = 0; j < 4; ++j)
                acc[i][j] = __builtin_amdgcn_mfma_f32_16x16x32_bf16(af[i], bfr[j], acc[i][j], 0, 0, 0);
    }
    #pragma unroll
    for (int i = 0; i < 4; ++i) {
        int rowb = row0 + wm * 64 + i * 16 + quad * 4;
        #pragma unroll
        for (int r = 0; r < 4; ++r) {
            int grow = rowb + r;
            if (grow < n) {
                #pragma unroll
                for (int j = 0; j < 4; ++j) {
                    int gcol = col0 + wn * 64 + j * 16 + l16;
                    C[(size_t)grow * H_F + gcol] = f2bf(acc[i][j][r]);
                }
            }
        }
    }
}

// ------------------------------------------------------------------
// GCN aggregation: wave per node, lane = 4 channels, edge loop unrolled x8.
// ------------------------------------------------------------------
__global__ __launch_bounds__(256) void aggregate_bf16(const ushort* __restrict__ hw,
                                                      const float* __restrict__ dinv,
                                                      const int* __restrict__ offsets,
                                                      const int2* __restrict__ csr_ew,
                                                      ushort* __restrict__ hout) {
    int w = threadIdx.x >> 6;
    int lane = threadIdx.x & 63;
    int i = blockIdx.x * 4 + w;
    if (i >= N_NODES) return;
    float di = dinv[i];
    const ushort* base = hw + (size_t)lane * 4;
    ushort4 sv = *(const ushort4*)(base + (size_t)i * H_F);
    float s = di * di;
    float a0 = s * bf2f(sv.x), a1 = s * bf2f(sv.y);
    float a2 = s * bf2f(sv.z), a3 = s * bf2f(sv.w);
    int t = offsets[i], end = offsets[i + 1];
    for (; t + 8 <= end; t += 8) {
        int2 e[8];
        ushort4 v[8];
        #pragma unroll
        for (int u = 0; u < 8; ++u) e[u] = csr_ew[t + u];
        #pragma unroll
        for (int u = 0; u < 8; ++u) v[u] = *(const ushort4*)(base + (size_t)e[u].x * H_F);
        #pragma unroll
        for (int u = 0; u < 8; ++u) {
            float wq = __int_as_float(e[u].y);
            a0 += wq * bf2f(v[u].x); a1 += wq * bf2f(v[u].y);
            a2 += wq * bf2f(v[u].z); a3 += wq * bf2f(v[u].w);
        }
    }
    for (; t < end; ++t) {
        int2 e0 = csr_ew[t];
        ushort4 v0 = *(const ushort4*)(base + (size_t)e0.x * H_F);
        float w0 = __int_as_float(e0.y);
        a0 += w0 * bf2f(v0.x); a1 += w0 * bf2f(v0.y);
        a2 += w0 * bf2f(v0.z); a3 += w0 * bf2f(v0.w);
    }
    ushort4 o;
    o.x = f2bf(fmaxf(a0, 0.f)); o.y = f2bf(fmaxf(a1, 0.f));
    o.z = f2bf(fmaxf(a2, 0.f)); o.w = f2bf(fmaxf(a3, 0.f));
    *(ushort4*)(hout + (size_t)i * H_F + lane * 4) = o;
}

// ------------------------------------------------------------------
// Pool: (graph, node-chunk) blocks, fp32 atomic partial sums.
// ------------------------------------------------------------------
__global__ __launch_bounds__(256) void pool_part(const ushort* __restrict__ h,
                                                 const int* __restrict__ gstart,
                                                 float* __restrict__ pooled) {
    int g = blockIdx.x;
    int s = gstart[g] + blockIdx.y * POOL_CHUNK;
    int e = min(gstart[g + 1], s + POOL_CHUNK);
    if (s >= e) return;
    int c = threadIdx.x;
    float sum = 0.f;
    for (int i = s; i < e; ++i) sum += bf2f(h[(size_t)i * H_F + c]);
    atomicAdd(&pooled[g * H_F + c], sum);
}

// ------------------------------------------------------------------
// Fused MLP head: mean-div + Wm1+relu + Wm2 + log_softmax/sigmoid/raw.
// One block per graph.
// ------------------------------------------------------------------
__global__ __launch_bounds__(256) void mlp_head_kernel(const float* __restrict__ pooled,
                                                       const int* __restrict__ gstart,
                                                       const float* __restrict__ Wm1,
                                                       const float* __restrict__ bm1,
                                                       const float* __restrict__ Wm2,
                                                       const float* __restrict__ bm2,
                                                       float* __restrict__ out) {
    __shared__ float p[H_F];
    __shared__ float h[H_F];
    __shared__ float lastv[OUT_F];
    __shared__ float stats[2];
    int g = blockIdx.x, j = threadIdx.x;
    int cnt = gstart[g + 1] - gstart[g];
    p[j] = pooled[g * H_F + j] / (float)max(cnt, 1);
    __syncthreads();
    float acc = bm1[j];
    for (int k = 0; k < H_F; ++k) acc += p[k] * Wm1[k * H_F + j];
    h[j] = fmaxf(acc, 0.f);
    __syncthreads();
    if (j < OUT_F) {
        float a = bm2[j];
        for (int k = 0; k < H_F; ++k) a += h[k] * Wm2[k * OUT_F + j];
        lastv[j] = a;
    }
    __syncthreads();
    if (j == 0) {
        float m = -1e30f;
        for (int o = 0; o < OUT_F; ++o) m = fmaxf(m, lastv[o]);
        float s = 0.f;
        for (int o = 0; o < OUT_F; ++o) s += expf(lastv[o] - m);
        stats[0] = m; stats[1] = logf(s);
    }
    __syncthreads();
    if (j < OUT_F) {
        float v = lastv[j];
        out[g * OUT_F + j] = v - stats[0] - stats[1];
        out[(size_t)N_G * OUT_F + g * OUT_F + j] = 1.f / (1.f + expf(-v));
        out[(size_t)2 * N_G * OUT_F + g * OUT_F + j] = v;
    }
}

// ------------------------------------------------------------------
extern "C" void kernel_launch(void* const* d_in, const int* in_sizes, int n_in,
                              void* d_out, int out_size, void* d_ws, size_t ws_size,
                              hipStream_t stream) {
    const float* x   = (const float*)d_in[0];
    const int* edge_index = (const int*)d_in[1];
    const int* batch = (const int*)d_in[3];
    const float* W0  = (const float*)d_in[4];
    const float* W1  = (const float*)d_in[5];
    const float* W2  = (const float*)d_in[6];
    const float* Wm1 = (const float*)d_in[7];
    const float* bm1 = (const float*)d_in[8];
    const float* Wm2 = (const float*)d_in[9];
    const float* bm2 = (const float*)d_in[10];
    float* out = (float*)d_out;

    char* ws = (char*)d_ws;
    size_t off = 0;
    auto alloc = [&](size_t bytes) -> void* {
        void* p = ws + off; off += (bytes + 255) & ~(size_t)255; return p;
    };
    ushort* xb     = (ushort*)alloc((size_t)N_PAD * IN_F * 2);
    ushort* bufA   = (ushort*)alloc((size_t)N_PAD * H_F * 2);
    ushort* bufB   = (ushort*)alloc((size_t)N_PAD * H_F * 2);
    ushort* W0t    = (ushort*)alloc((size_t)H_F * IN_F * 2);
    ushort* W1t    = (ushort*)alloc((size_t)H_F * H_F * 2);
    ushort* W2t    = (ushort*)alloc((size_t)H_F * H_F * 2);
    float* dinv    = (float*)alloc((size_t)N_NODES * 4);
    int*   counts  = (int*)alloc((size_t)N_NODES * 4);
    int*   offsets = (int*)alloc((size_t)(N_NODES + 1) * 4);
    int*   cursor  = (int*)alloc((size_t)N_NODES * 4);
    int2*  csr_ew  = (int2*)alloc((size_t)N_EDGES * 8);
    int*   csum    = (int*)alloc((size_t)256 * 4);
    int*   gstart  = (int*)alloc((size_t)(N_G + 1) * 4);
    float* pooled  = (float*)alloc((size_t)N_G * H_F * 4);

    const int* row = edge_index;
    const int* col = edge_index + N_EDGES;

    hipMemsetAsync(counts, 0, (size_t)N_NODES * 4, stream);
    hipMemsetAsync(pooled, 0, (size_t)N_G * H_F * 4, stream);

    prep_kernel<<<PREP_GS, 256, 0, stream>>>(col, counts, x, xb,
                                             W0, W0t, W1, W1t, W2, W2t,
                                             batch, gstart);
    chunk_reduce<<<NCHUNKS, 256, 0, stream>>>(counts, csum, N_NODES);
    scan_dinv_kernel<<<NCHUNKS, 256, 0, stream>>>(counts, csum, offsets, dinv,
                                                  cursor, N_NODES);
    fill_csr_kernel<<<(N_EDGES + 255) / 256, 256, 0, stream>>>(row, col, offsets, cursor,
                                                               dinv, csr_ew, N_EDGES);

    dim3 gg(N_PAD / 128, H_F / 128);
    int agg_blocks = (N_NODES + 3) / 4;
    gemm_mfma<IN_F><<<gg, 256, 0, stream>>>(xb, W0t, bufA, N_NODES);
    aggregate_bf16<<<agg_blocks, 256, 0, stream>>>(bufA, dinv, offsets, csr_ew, bufB);
    gemm_mfma<H_F><<<gg, 256, 0, stream>>>(bufB, W1t, bufA, N_NODES);
    aggregate_bf16<<<agg_blocks, 256, 0, stream>>>(bufA, dinv, offsets, csr_ew, bufB);
    gemm_mfma<H_F><<<gg, 256, 0, stream>>>(bufB, W2t, bufA, N_NODES);
    aggregate_bf16<<<agg_blocks, 256, 0, stream>>>(bufA, dinv, offsets, csr_ew, bufB);

    dim3 pg(N_G, POOL_MAXCHUNKS);
    pool_part<<<pg, 256, 0, stream>>>(bufB, gstart, pooled);
    mlp_head_kernel<<<N_G, 256, 0, stream>>>(pooled, gstart, Wm1, bm1, Wm2, bm2, out);
}

// Round 6
// 435.307 us; speedup vs baseline: 2.4522x; 1.0458x over previous
//
#include <hip/hip_runtime.h>
#include <math.h>

#define N_NODES 50000
#define N_PAD   50048          // padded to multiple of 128 for GEMM tiles
#define N_EDGES 800000
#define IN_F 128
#define H_F 256
#define OUT_F 10
#define N_G 128
#define POOL_CHUNK 128
#define POOL_MAXCHUNKS 16
#define NCHUNKS 196            // ceil(N_NODES/256)

typedef __attribute__((ext_vector_type(8))) short bf16x8;
typedef __attribute__((ext_vector_type(4))) float f32x4;

__device__ inline float bf2f(ushort u) {
    union { unsigned int u; float f; } v; v.u = ((unsigned int)u) << 16; return v.f;
}
__device__ inline ushort f2bf(float x) {
    union { float f; unsigned int u; } v; v.f = x;
    unsigned int r = v.u + 0x7fff + ((v.u >> 16) & 1);
    return (ushort)(r >> 16);
}

// async global->LDS, 16 B per lane; lds dest = wave-uniform base + lane*16
__device__ inline void gl2lds16(const ushort* g, ushort* l) {
    __builtin_amdgcn_global_load_lds(
        (const __attribute__((address_space(1))) unsigned int*)g,
        (__attribute__((address_space(3))) unsigned int*)l,
        16, 0, 0);
}

// ------------------------------------------------------------------
// Mega-fused prep (block roles by blockIdx range)
// ------------------------------------------------------------------
#define PREP_CE   3125
#define PREP_CV   (PREP_CE + 6250)
#define PREP_T0   (PREP_CV + 128)
#define PREP_T1   (PREP_T0 + 256)
#define PREP_T2   (PREP_T1 + 256)
#define PREP_GS   (PREP_T2 + NCHUNKS)

__global__ __launch_bounds__(256) void prep_kernel(
    const int* __restrict__ col, int* __restrict__ counts,
    const float* __restrict__ x, ushort* __restrict__ xb,
    const float* __restrict__ W0, ushort* __restrict__ W0t,
    const float* __restrict__ W1, ushort* __restrict__ W1t,
    const float* __restrict__ W2, ushort* __restrict__ W2t,
    const int* __restrict__ batch, int* __restrict__ gstart) {
    int b = blockIdx.x;
    int tid = threadIdx.x;
    if (b < PREP_CE) {
        int e = b * 256 + tid;
        if (e < N_EDGES) atomicAdd(&counts[col[e]], 1);
    } else if (b < PREP_CV) {
        int i = (b - PREP_CE) * 256 + tid;      // < 1,600,000 exactly
        float4 v = *(const float4*)(x + (size_t)i * 4);
        ushort4 o;
        o.x = f2bf(v.x); o.y = f2bf(v.y); o.z = f2bf(v.z); o.w = f2bf(v.w);
        *(ushort4*)(xb + (size_t)i * 4) = o;
    } else if (b < PREP_T0) {
        int idx = (b - PREP_CV) * 256 + tid;    // < 32768
        int k = idx >> 8, nn = idx & 255;       // K=128, Nc=256
        W0t[nn * IN_F + k] = f2bf(W0[idx]);
    } else if (b < PREP_T1) {
        int idx = (b - PREP_T0) * 256 + tid;    // < 65536
        int k = idx >> 8, nn = idx & 255;
        W1t[nn * H_F + k] = f2bf(W1[idx]);
    } else if (b < PREP_T2) {
        int idx = (b - PREP_T1) * 256 + tid;
        int k = idx >> 8, nn = idx & 255;
        W2t[nn * H_F + k] = f2bf(W2[idx]);
    } else {
        int i = (b - PREP_T2) * 256 + tid;
        if (i >= N_NODES) return;
        int bb = batch[i];
        if (i == 0) {
            for (int g = 0; g <= bb; ++g) gstart[g] = 0;
        } else {
            int p = batch[i - 1];
            if (p != bb) { for (int g = p + 1; g <= bb; ++g) gstart[g] = i; }
        }
        if (i == N_NODES - 1) {
            for (int g = bb + 1; g <= N_G; ++g) gstart[g] = N_NODES;
        }
    }
}

// ------------------------------------------------------------------
// per-chunk sums of counts (196 blocks)
// ------------------------------------------------------------------
__global__ __launch_bounds__(256) void chunk_reduce(const int* __restrict__ counts,
                                                    int* __restrict__ csum, int n) {
    int i = blockIdx.x * 256 + threadIdx.x;
    int v = (i < n) ? counts[i] : 0;
    #pragma unroll
    for (int off = 32; off; off >>= 1) v += __shfl_down(v, off);
    __shared__ int ws[4];
    if ((threadIdx.x & 63) == 0) ws[threadIdx.x >> 6] = v;
    __syncthreads();
    if (threadIdx.x == 0) csum[blockIdx.x] = ws[0] + ws[1] + ws[2] + ws[3];
}

// ------------------------------------------------------------------
// scan + dinv + cursor-zero, fully parallel (196 blocks)
// ------------------------------------------------------------------
__global__ __launch_bounds__(256) void scan_dinv_kernel(const int* __restrict__ counts,
                                                        const int* __restrict__ csum,
                                                        int* __restrict__ offsets,
                                                        float* __restrict__ dinv,
                                                        int* __restrict__ cursor, int n) {
    int tid = threadIdx.x;
    int lane = tid & 63, wid = tid >> 6;
    int cv = (tid < NCHUNKS) ? csum[tid] : 0;
    int xc = cv;
    #pragma unroll
    for (int off = 1; off < 64; off <<= 1) {
        int t = __shfl_up(xc, off);
        if (lane >= off) xc += t;
    }
    __shared__ int cw[4], cpre[4];
    __shared__ int cexcl[256];
    if (lane == 63) cw[wid] = xc;
    __syncthreads();
    if (tid == 0) { int s = 0; for (int k = 0; k < 4; ++k) { cpre[k] = s; s += cw[k]; } }
    __syncthreads();
    cexcl[tid] = cpre[wid] + xc - cv;
    __syncthreads();
    int base = cexcl[blockIdx.x];
    int i = blockIdx.x * 256 + tid;
    int v = (i < n) ? counts[i] : 0;
    int x = v;
    #pragma unroll
    for (int off = 1; off < 64; off <<= 1) {
        int t = __shfl_up(x, off);
        if (lane >= off) x += t;
    }
    __shared__ int wsum[4], wpre[4];
    if (lane == 63) wsum[wid] = x;
    __syncthreads();
    if (tid == 0) { int s = 0; for (int k = 0; k < 4; ++k) { wpre[k] = s; s += wsum[k]; } }
    __syncthreads();
    if (i < n) {
        offsets[i] = base + wpre[wid] + x - v;   // exclusive
        dinv[i] = rsqrtf((float)(v + 1));
        cursor[i] = 0;
    }
    if (blockIdx.x == 0 && tid == 0) offsets[n] = N_EDGES;
}

// CSR with packed (source row, edge weight) — weight = dinv[dst]*dinv[src]
__global__ void fill_csr_kernel(const int* __restrict__ row, const int* __restrict__ col,
                                const int* __restrict__ offsets, int* __restrict__ cursor,
                                const float* __restrict__ dinv,
                                int2* __restrict__ csr_ew, int E) {
    int e = blockIdx.x * blockDim.x + threadIdx.x;
    if (e < E) {
        int c = col[e];
        int r = row[e];
        int p = atomicAdd(&cursor[c], 1);
        float w = dinv[c] * dinv[r];
        csr_ew[offsets[c] + p] = make_int2(r, __float_as_int(w));
    }
}

// ------------------------------------------------------------------
// bf16 MFMA GEMM: C[N_PAD x 256] = A[N_PAD x K] @ Bt^T   (Bt is [256][K])
// 128x128 tile / block (4 waves 2x2), BK=64 (two 8 KB k-planes per operand,
// each plane in the proven [row][32k] layout), async global_load_lds staging.
// ------------------------------------------------------------------
template <int K, bool RELU>
__global__ __launch_bounds__(256) void gemm_mfma(const ushort* __restrict__ A,
                                                 const ushort* __restrict__ Bt,
                                                 ushort* __restrict__ C,
                                                 int n) {
    __shared__ ushort As[2 * 4096];   // plane h: [128 rows][32 k]
    __shared__ ushort Bs[2 * 4096];
    int tid = threadIdx.x;
    int lane = tid & 63;
    int w = tid >> 6;
    int wm = w & 1, wn = w >> 1;
    int l16 = lane & 15, quad = lane >> 4;
    int row0 = blockIdx.x * 128;
    int col0 = blockIdx.y * 128;
    f32x4 acc[4][4] = {};

    int lrow = lane >> 2;          // 0..15 within 16-row chunk
    int lk   = (lane & 3) * 8;     // 0,8,16,24 within 32-k plane

    #pragma unroll
    for (int k0 = 0; k0 < K; k0 += 64) {
        __syncthreads();
        #pragma unroll
        for (int c = 0; c < 4; ++c) {
            int chunk = c * 4 + w;         // 0..15 (wave-uniform)
            int h = chunk >> 3;            // k-plane
            int rg = chunk & 7;            // 16-row group
            const ushort* ga = A + (size_t)(row0 + rg * 16 + lrow) * K + k0 + h * 32 + lk;
            const ushort* gb = Bt + (size_t)(col0 + rg * 16 + lrow) * K + k0 + h * 32 + lk;
            gl2lds16(ga, As + h * 4096 + rg * 512);
            gl2lds16(gb, Bs + h * 4096 + rg * 512);
        }
        __syncthreads();
        #pragma unroll
        for (int h = 0; h < 2; ++h) {
            bf16x8 af[4], bfr[4];
            #pragma unroll
            for (int i = 0; i < 4; ++i)
                af[i] = *(bf16x8*)&As[h * 4096 + (wm * 64 + i * 16 + l16) * 32 + quad * 8];
            #pragma unroll
            for (int j = 0; j < 4; ++j)
                bfr[j] = *(bf16x8*)&Bs[h * 4096 + (wn * 64 + j * 16 + l16) * 32 + quad * 8];
            #pragma unroll
            for (int i = 0; i < 4; ++i)
                #pragma unroll
                for (int j = 0; j < 4; ++j)
                    acc[i][j] = __builtin_amdgcn_mfma_f32_16x16x32_bf16(af[i], bfr[j], acc[i][j], 0, 0, 0);
        }
    }
    // epilogue: C/D layout col=lane&15, row=quad*4+reg; rows < N_PAD always writable
    #pragma unroll
    for (int i = 0; i < 4; ++i) {
        int rowb = row0 + wm * 64 + i * 16 + quad * 4;
        #pragma unroll
        for (int r = 0; r < 4; ++r) {
            int grow = rowb + r;
            #pragma unroll
            for (int j = 0; j < 4; ++j) {
                int gcol = col0 + wn * 64 + j * 16 + l16;
                float v = acc[i][j][r];
                if (RELU) v = fmaxf(v, 0.f);
                C[(size_t)grow * H_F + gcol] = f2bf(v);
            }
        }
    }
}

// ------------------------------------------------------------------
// GCN aggregation, 128-ch (layer-0, pre-GEMM), NO relu.
// wave per node, lane = 2 channels (uint load), edge loop unrolled x8.
// ------------------------------------------------------------------
__global__ __launch_bounds__(256) void aggregate128(const ushort* __restrict__ hw,
                                                    const float* __restrict__ dinv,
                                                    const int* __restrict__ offsets,
                                                    const int2* __restrict__ csr_ew,
                                                    ushort* __restrict__ hout) {
    int w = threadIdx.x >> 6;
    int lane = threadIdx.x & 63;
    int i = blockIdx.x * 4 + w;
    if (i >= N_NODES) return;
    float di = dinv[i];
    const ushort* base = hw + (size_t)lane * 2;
    unsigned int su = *(const unsigned int*)(base + (size_t)i * IN_F);
    float s = di * di;
    float a0 = s * bf2f((ushort)(su & 0xffff));
    float a1 = s * bf2f((ushort)(su >> 16));
    int t = offsets[i], end = offsets[i + 1];
    for (; t + 8 <= end; t += 8) {
        int2 e[8];
        unsigned int v[8];
        #pragma unroll
        for (int u = 0; u < 8; ++u) e[u] = csr_ew[t + u];
        #pragma unroll
        for (int u = 0; u < 8; ++u)
            v[u] = *(const unsigned int*)(base + (size_t)e[u].x * IN_F);
        #pragma unroll
        for (int u = 0; u < 8; ++u) {
            float wq = __int_as_float(e[u].y);
            a0 += wq * bf2f((ushort)(v[u] & 0xffff));
            a1 += wq * bf2f((ushort)(v[u] >> 16));
        }
    }
    for (; t < end; ++t) {
        int2 e0 = csr_ew[t];
        unsigned int v0 = *(const unsigned int*)(base + (size_t)e0.x * IN_F);
        float wq = __int_as_float(e0.y);
        a0 += wq * bf2f((ushort)(v0 & 0xffff));
        a1 += wq * bf2f((ushort)(v0 >> 16));
    }
    unsigned int o = (unsigned int)f2bf(a0) | ((unsigned int)f2bf(a1) << 16);
    *(unsigned int*)(hout + (size_t)i * IN_F + lane * 2) = o;
}

// ------------------------------------------------------------------
// GCN aggregation, 256-ch, + relu. wave per node, lane = 4 channels.
// ------------------------------------------------------------------
__global__ __launch_bounds__(256) void aggregate_bf16(const ushort* __restrict__ hw,
                                                      const float* __restrict__ dinv,
                                                      const int* __restrict__ offsets,
                                                      const int2* __restrict__ csr_ew,
                                                      ushort* __restrict__ hout) {
    int w = threadIdx.x >> 6;
    int lane = threadIdx.x & 63;
    int i = blockIdx.x * 4 + w;
    if (i >= N_NODES) return;
    float di = dinv[i];
    const ushort* base = hw + (size_t)lane * 4;
    ushort4 sv = *(const ushort4*)(base + (size_t)i * H_F);
    float s = di * di;
    float a0 = s * bf2f(sv.x), a1 = s * bf2f(sv.y);
    float a2 = s * bf2f(sv.z), a3 = s * bf2f(sv.w);
    int t = offsets[i], end = offsets[i + 1];
    for (; t + 4 <= end; t += 4) {
        int2 e0 = csr_ew[t + 0], e1 = csr_ew[t + 1];
        int2 e2 = csr_ew[t + 2], e3 = csr_ew[t + 3];
        ushort4 v0 = *(const ushort4*)(base + (size_t)e0.x * H_F);
        ushort4 v1 = *(const ushort4*)(base + (size_t)e1.x * H_F);
        ushort4 v2 = *(const ushort4*)(base + (size_t)e2.x * H_F);
        ushort4 v3 = *(const ushort4*)(base + (size_t)e3.x * H_F);
        float w0 = __int_as_float(e0.y), w1 = __int_as_float(e1.y);
        float w2 = __int_as_float(e2.y), w3 = __int_as_float(e3.y);
        a0 += w0 * bf2f(v0.x); a1 += w0 * bf2f(v0.y);
        a2 += w0 * bf2f(v0.z); a3 += w0 * bf2f(v0.w);
        a0 += w1 * bf2f(v1.x); a1 += w1 * bf2f(v1.y);
        a2 += w1 * bf2f(v1.z); a3 += w1 * bf2f(v1.w);
        a0 += w2 * bf2f(v2.x); a1 += w2 * bf2f(v2.y);
        a2 += w2 * bf2f(v2.z); a3 += w2 * bf2f(v2.w);
        a0 += w3 * bf2f(v3.x); a1 += w3 * bf2f(v3.y);
        a2 += w3 * bf2f(v3.z); a3 += w3 * bf2f(v3.w);
    }
    for (; t < end; ++t) {
        int2 e0 = csr_ew[t];
        ushort4 v0 = *(const ushort4*)(base + (size_t)e0.x * H_F);
        float w0 = __int_as_float(e0.y);
        a0 += w0 * bf2f(v0.x); a1 += w0 * bf2f(v0.y);
        a2 += w0 * bf2f(v0.z); a3 += w0 * bf2f(v0.w);
    }
    ushort4 o;
    o.x = f2bf(fmaxf(a0, 0.f)); o.y = f2bf(fmaxf(a1, 0.f));
    o.z = f2bf(fmaxf(a2, 0.f)); o.w = f2bf(fmaxf(a3, 0.f));
    *(ushort4*)(hout + (size_t)i * H_F + lane * 4) = o;
}

// ------------------------------------------------------------------
// Pool: (graph, node-chunk) blocks, fp32 atomic partial sums.
// ------------------------------------------------------------------
__global__ __launch_bounds__(256) void pool_part(const ushort* __restrict__ h,
                                                 const int* __restrict__ gstart,
                                                 float* __restrict__ pooled) {
    int g = blockIdx.x;
    int s = gstart[g] + blockIdx.y * POOL_CHUNK;
    int e = min(gstart[g + 1], s + POOL_CHUNK);
    if (s >= e) return;
    int c = threadIdx.x;
    float sum = 0.f;
    for (int i = s; i < e; ++i) sum += bf2f(h[(size_t)i * H_F + c]);
    atomicAdd(&pooled[g * H_F + c], sum);
}

// ------------------------------------------------------------------
// Fused MLP head
// ------------------------------------------------------------------
__global__ __launch_bounds__(256) void mlp_head_kernel(const float* __restrict__ pooled,
                                                       const int* __restrict__ gstart,
                                                       const float* __restrict__ Wm1,
                                                       const float* __restrict__ bm1,
                                                       const float* __restrict__ Wm2,
                                                       const float* __restrict__ bm2,
                                                       float* __restrict__ out) {
    __shared__ float p[H_F];
    __shared__ float h[H_F];
    __shared__ float lastv[OUT_F];
    __shared__ float stats[2];
    int g = blockIdx.x, j = threadIdx.x;
    int cnt = gstart[g + 1] - gstart[g];
    p[j] = pooled[g * H_F + j] / (float)max(cnt, 1);
    __syncthreads();
    float acc = bm1[j];
    for (int k = 0; k < H_F; ++k) acc += p[k] * Wm1[k * H_F + j];
    h[j] = fmaxf(acc, 0.f);
    __syncthreads();
    if (j < OUT_F) {
        float a = bm2[j];
        for (int k = 0; k < H_F; ++k) a += h[k] * Wm2[k * OUT_F + j];
        lastv[j] = a;
    }
    __syncthreads();
    if (j == 0) {
        float m = -1e30f;
        for (int o = 0; o < OUT_F; ++o) m = fmaxf(m, lastv[o]);
        float s = 0.f;
        for (int o = 0; o < OUT_F; ++o) s += expf(lastv[o] - m);
        stats[0] = m; stats[1] = logf(s);
    }
    __syncthreads();
    if (j < OUT_F) {
        float v = lastv[j];
        out[g * OUT_F + j] = v - stats[0] - stats[1];
        out[(size_t)N_G * OUT_F + g * OUT_F + j] = 1.f / (1.f + expf(-v));
        out[(size_t)2 * N_G * OUT_F + g * OUT_F + j] = v;
    }
}

// ------------------------------------------------------------------
extern "C" void kernel_launch(void* const* d_in, const int* in_sizes, int n_in,
                              void* d_out, int out_size, void* d_ws, size_t ws_size,
                              hipStream_t stream) {
    const float* x   = (const float*)d_in[0];
    const int* edge_index = (const int*)d_in[1];
    const int* batch = (const int*)d_in[3];
    const float* W0  = (const float*)d_in[4];
    const float* W1  = (const float*)d_in[5];
    const float* W2  = (const float*)d_in[6];
    const float* Wm1 = (const float*)d_in[7];
    const float* bm1 = (const float*)d_in[8];
    const float* Wm2 = (const float*)d_in[9];
    const float* bm2 = (const float*)d_in[10];
    float* out = (float*)d_out;

    char* ws = (char*)d_ws;
    size_t off = 0;
    auto alloc = [&](size_t bytes) -> void* {
        void* p = ws + off; off += (bytes + 255) & ~(size_t)255; return p;
    };
    ushort* xb     = (ushort*)alloc((size_t)N_PAD * IN_F * 2);
    ushort* bufA   = (ushort*)alloc((size_t)N_PAD * H_F * 2);
    ushort* bufB   = (ushort*)alloc((size_t)N_PAD * H_F * 2);
    ushort* W0t    = (ushort*)alloc((size_t)H_F * IN_F * 2);
    ushort* W1t    = (ushort*)alloc((size_t)H_F * H_F * 2);
    ushort* W2t    = (ushort*)alloc((size_t)H_F * H_F * 2);
    float* dinv    = (float*)alloc((size_t)N_NODES * 4);
    int*   counts  = (int*)alloc((size_t)N_NODES * 4);
    int*   offsets = (int*)alloc((size_t)(N_NODES + 1) * 4);
    int*   cursor  = (int*)alloc((size_t)N_NODES * 4);
    int2*  csr_ew  = (int2*)alloc((size_t)N_EDGES * 8);
    int*   csum    = (int*)alloc((size_t)256 * 4);
    int*   gstart  = (int*)alloc((size_t)(N_G + 1) * 4);
    float* pooled  = (float*)alloc((size_t)N_G * H_F * 4);

    const int* row = edge_index;
    const int* col = edge_index + N_EDGES;

    hipMemsetAsync(counts, 0, (size_t)N_NODES * 4, stream);
    hipMemsetAsync(pooled, 0, (size_t)N_G * H_F * 4, stream);

    prep_kernel<<<PREP_GS, 256, 0, stream>>>(col, counts, x, xb,
                                             W0, W0t, W1, W1t, W2, W2t,
                                             batch, gstart);
    chunk_reduce<<<NCHUNKS, 256, 0, stream>>>(counts, csum, N_NODES);
    scan_dinv_kernel<<<NCHUNKS, 256, 0, stream>>>(counts, csum, offsets, dinv,
                                                  cursor, N_NODES);
    fill_csr_kernel<<<(N_EDGES + 255) / 256, 256, 0, stream>>>(row, col, offsets, cursor,
                                                               dinv, csr_ew, N_EDGES);

    dim3 gg(N_PAD / 128, H_F / 128);
    int agg_blocks = (N_NODES + 3) / 4;
    // layer 0: aggregate-first (linear ops commute), relu in GEMM epilogue
    aggregate128<<<agg_blocks, 256, 0, stream>>>(xb, dinv, offsets, csr_ew, bufB);
    gemm_mfma<IN_F, true><<<gg, 256, 0, stream>>>(bufB, W0t, bufA, N_NODES);
    // layer 1
    gemm_mfma<H_F, false><<<gg, 256, 0, stream>>>(bufA, W1t, bufB, N_NODES);
    aggregate_bf16<<<agg_blocks, 256, 0, stream>>>(bufB, dinv, offsets, csr_ew, bufA);
    // layer 2
    gemm_mfma<H_F, false><<<gg, 256, 0, stream>>>(bufA, W2t, bufB, N_NODES);
    aggregate_bf16<<<agg_blocks, 256, 0, stream>>>(bufB, dinv, offsets, csr_ew, bufA);

    dim3 pg(N_G, POOL_MAXCHUNKS);
    pool_part<<<pg, 256, 0, stream>>>(bufA, gstart, pooled);
    mlp_head_kernel<<<N_G, 256, 0, stream>>>(pooled, gstart, Wm1, bm1, Wm2, bm2, out);
}

// Round 8
// 379.804 us; speedup vs baseline: 2.8105x; 1.1461x over previous
//
#include <hip/hip_runtime.h>
#include <math.h>

#define N_NODES 50000
#define N_PAD   50048          // padded to multiple of 128 for GEMM tiles
#define N_EDGES 800000
#define IN_F 128
#define H_F 256
#define OUT_F 10
#define N_G 128
#define POOL_CHUNK 128
#define POOL_MAXCHUNKS 16
#define NCHUNKS 196            // ceil(N_NODES/256)

typedef __attribute__((ext_vector_type(4))) float f32x4;
typedef __attribute__((ext_vector_type(2))) float f32x2;
typedef unsigned char u8;

// ---- fp8 e4m3 (OCP on gfx950) helpers: HW packed converts.
// NOTE: the word-select operand must be an immediate -> separate lo/hi fns.
__device__ inline f32x2 fp8x2_f32_lo(unsigned int v) {
    return __builtin_amdgcn_cvt_pk_f32_fp8(v, false);
}
__device__ inline f32x2 fp8x2_f32_hi(unsigned int v) {
    return __builtin_amdgcn_cvt_pk_f32_fp8(v, true);
}
__device__ inline unsigned int f32_fp8x2_lo(float a, float b, unsigned int old) {
    return __builtin_amdgcn_cvt_pk_fp8_f32(a, b, old, false);
}
__device__ inline unsigned int f32_fp8x2_hi(float a, float b, unsigned int old) {
    return __builtin_amdgcn_cvt_pk_fp8_f32(a, b, old, true);
}
__device__ inline u8 f32_fp8(float a) {
    return (u8)(f32_fp8x2_lo(a, a, 0u) & 0xff);
}

// async global->LDS, 16 B per lane; lds dest = wave-uniform base + lane*16
__device__ inline void gl2lds16(const void* g, void* l) {
    __builtin_amdgcn_global_load_lds(
        (const __attribute__((address_space(1))) unsigned int*)g,
        (__attribute__((address_space(3))) unsigned int*)l,
        16, 0, 0);
}

// ------------------------------------------------------------------
// Mega-fused prep (block roles by blockIdx range)
// ------------------------------------------------------------------
#define PREP_CE   3125
#define PREP_CV   (PREP_CE + 6250)
#define PREP_T0   (PREP_CV + 128)
#define PREP_T1   (PREP_T0 + 256)
#define PREP_T2   (PREP_T1 + 256)
#define PREP_GS   (PREP_T2 + NCHUNKS)

__global__ __launch_bounds__(256) void prep_kernel(
    const int* __restrict__ col, int* __restrict__ counts,
    const float* __restrict__ x, u8* __restrict__ xb,
    const float* __restrict__ W0, u8* __restrict__ W0t,
    const float* __restrict__ W1, u8* __restrict__ W1t,
    const float* __restrict__ W2, u8* __restrict__ W2t,
    const int* __restrict__ batch, int* __restrict__ gstart) {
    int b = blockIdx.x;
    int tid = threadIdx.x;
    if (b < PREP_CE) {
        int e = b * 256 + tid;
        if (e < N_EDGES) atomicAdd(&counts[col[e]], 1);
    } else if (b < PREP_CV) {
        int i = (b - PREP_CE) * 256 + tid;      // < 1,600,000 exactly
        float4 v = *(const float4*)(x + (size_t)i * 4);
        unsigned int p = f32_fp8x2_lo(v.x, v.y, 0u);
        p = f32_fp8x2_hi(v.z, v.w, p);
        *(unsigned int*)(xb + (size_t)i * 4) = p;
    } else if (b < PREP_T0) {
        int idx = (b - PREP_CV) * 256 + tid;    // < 32768
        int k = idx >> 8, nn = idx & 255;       // K=128, Nc=256
        W0t[nn * IN_F + k] = f32_fp8(W0[idx]);
    } else if (b < PREP_T1) {
        int idx = (b - PREP_T0) * 256 + tid;    // < 65536
        int k = idx >> 8, nn = idx & 255;
        W1t[nn * H_F + k] = f32_fp8(W1[idx]);
    } else if (b < PREP_T2) {
        int idx = (b - PREP_T1) * 256 + tid;
        int k = idx >> 8, nn = idx & 255;
        W2t[nn * H_F + k] = f32_fp8(W2[idx]);
    } else {
        int i = (b - PREP_T2) * 256 + tid;
        if (i >= N_NODES) return;
        int bb = batch[i];
        if (i == 0) {
            for (int g = 0; g <= bb; ++g) gstart[g] = 0;
        } else {
            int p = batch[i - 1];
            if (p != bb) { for (int g = p + 1; g <= bb; ++g) gstart[g] = i; }
        }
        if (i == N_NODES - 1) {
            for (int g = bb + 1; g <= N_G; ++g) gstart[g] = N_NODES;
        }
    }
}

// ------------------------------------------------------------------
// per-chunk sums of counts (196 blocks)
// ------------------------------------------------------------------
__global__ __launch_bounds__(256) void chunk_reduce(const int* __restrict__ counts,
                                                    int* __restrict__ csum, int n) {
    int i = blockIdx.x * 256 + threadIdx.x;
    int v = (i < n) ? counts[i] : 0;
    #pragma unroll
    for (int off = 32; off; off >>= 1) v += __shfl_down(v, off);
    __shared__ int ws[4];
    if ((threadIdx.x & 63) == 0) ws[threadIdx.x >> 6] = v;
    __syncthreads();
    if (threadIdx.x == 0) csum[blockIdx.x] = ws[0] + ws[1] + ws[2] + ws[3];
}

// ------------------------------------------------------------------
// scan + dinv + cursor-zero, fully parallel (196 blocks)
// ------------------------------------------------------------------
__global__ __launch_bounds__(256) void scan_dinv_kernel(const int* __restrict__ counts,
                                                        const int* __restrict__ csum,
                                                        int* __restrict__ offsets,
                                                        float* __restrict__ dinv,
                                                        int* __restrict__ cursor, int n) {
    int tid = threadIdx.x;
    int lane = tid & 63, wid = tid >> 6;
    int cv = (tid < NCHUNKS) ? csum[tid] : 0;
    int xc = cv;
    #pragma unroll
    for (int off = 1; off < 64; off <<= 1) {
        int t = __shfl_up(xc, off);
        if (lane >= off) xc += t;
    }
    __shared__ int cw[4], cpre[4];
    __shared__ int cexcl[256];
    if (lane == 63) cw[wid] = xc;
    __syncthreads();
    if (tid == 0) { int s = 0; for (int k = 0; k < 4; ++k) { cpre[k] = s; s += cw[k]; } }
    __syncthreads();
    cexcl[tid] = cpre[wid] + xc - cv;
    __syncthreads();
    int base = cexcl[blockIdx.x];
    int i = blockIdx.x * 256 + tid;
    int v = (i < n) ? counts[i] : 0;
    int x = v;
    #pragma unroll
    for (int off = 1; off < 64; off <<= 1) {
        int t = __shfl_up(x, off);
        if (lane >= off) x += t;
    }
    __shared__ int wsum[4], wpre[4];
    if (lane == 63) wsum[wid] = x;
    __syncthreads();
    if (tid == 0) { int s = 0; for (int k = 0; k < 4; ++k) { wpre[k] = s; s += wsum[k]; } }
    __syncthreads();
    if (i < n) {
        offsets[i] = base + wpre[wid] + x - v;   // exclusive
        dinv[i] = rsqrtf((float)(v + 1));
        cursor[i] = 0;
    }
    if (blockIdx.x == 0 && tid == 0) offsets[n] = N_EDGES;
}

// CSR with packed (source row, edge weight) — weight = dinv[dst]*dinv[src]
__global__ void fill_csr_kernel(const int* __restrict__ row, const int* __restrict__ col,
                                const int* __restrict__ offsets, int* __restrict__ cursor,
                                const float* __restrict__ dinv,
                                int2* __restrict__ csr_ew, int E) {
    int e = blockIdx.x * blockDim.x + threadIdx.x;
    if (e < E) {
        int c = col[e];
        int r = row[e];
        int p = atomicAdd(&cursor[c], 1);
        float w = dinv[c] * dinv[r];
        csr_ew[offsets[c] + p] = make_int2(r, __float_as_int(w));
    }
}

// ------------------------------------------------------------------
// fp8 MFMA GEMM: C[N_PAD x 256] = A[N_PAD x K] @ Bt^T   (Bt is [256][K], fp8)
// 128x128 tile / block (4 waves 2x2), BK=64: two 4 KB k-planes per operand,
// plane layout [128 rows][32 k-bytes], async global_load_lds staging.
// mfma_f32_16x16x32_fp8_fp8: 8 fp8/lane (2 VGPR), same index map as bf16.
// ------------------------------------------------------------------
template <int K, bool RELU>
__global__ __launch_bounds__(256) void gemm_fp8(const u8* __restrict__ A,
                                                const u8* __restrict__ Bt,
                                                u8* __restrict__ C) {
    __shared__ u8 As[2 * 4096];
    __shared__ u8 Bs[2 * 4096];
    int tid = threadIdx.x;
    int lane = tid & 63;
    int w = tid >> 6;
    int wm = w & 1, wn = w >> 1;
    int l16 = lane & 15, quad = lane >> 4;
    int row0 = blockIdx.x * 128;
    int col0 = blockIdx.y * 128;
    f32x4 acc[4][4] = {};

    int sr = tid >> 1;             // staging row 0..127
    int sh = (tid & 1) * 16;       // half-row byte offset

    #pragma unroll
    for (int k0 = 0; k0 < K; k0 += 64) {
        __syncthreads();
        #pragma unroll
        for (int q = 0; q < 2; ++q) {   // k-plane
            const u8* ga = A + (size_t)(row0 + sr) * K + k0 + q * 32 + sh;
            const u8* gb = Bt + (size_t)(col0 + sr) * K + k0 + q * 32 + sh;
            gl2lds16(ga, As + q * 4096 + w * 1024);
            gl2lds16(gb, Bs + q * 4096 + w * 1024);
        }
        __syncthreads();
        #pragma unroll
        for (int h = 0; h < 2; ++h) {
            long af[4], bfr[4];
            #pragma unroll
            for (int i = 0; i < 4; ++i)
                af[i] = *(const long*)&As[h * 4096 + (wm * 64 + i * 16 + l16) * 32 + quad * 8];
            #pragma unroll
            for (int j = 0; j < 4; ++j)
                bfr[j] = *(const long*)&Bs[h * 4096 + (wn * 64 + j * 16 + l16) * 32 + quad * 8];
            #pragma unroll
            for (int i = 0; i < 4; ++i)
                #pragma unroll
                for (int j = 0; j < 4; ++j)
                    acc[i][j] = __builtin_amdgcn_mfma_f32_16x16x32_fp8_fp8(af[i], bfr[j], acc[i][j], 0, 0, 0);
        }
    }
    // epilogue: C/D layout col=lane&15, row=quad*4+reg (dtype-independent)
    #pragma unroll
    for (int i = 0; i < 4; ++i) {
        int rowb = row0 + wm * 64 + i * 16 + quad * 4;
        #pragma unroll
        for (int r = 0; r < 4; ++r) {
            int grow = rowb + r;
            #pragma unroll
            for (int j = 0; j < 4; ++j) {
                int gcol = col0 + wn * 64 + j * 16 + l16;
                float v = acc[i][j][r];
                if (RELU) v = fmaxf(v, 0.f);
                C[(size_t)grow * H_F + gcol] = f32_fp8(v);
            }
        }
    }
}

// ------------------------------------------------------------------
// GCN aggregation, 128-ch fp8 (layer-0, pre-GEMM), NO relu.
// wave per node, lane = 2 channels (2 B load), edge loop unrolled x8.
// ------------------------------------------------------------------
__global__ __launch_bounds__(256) void aggregate128(const u8* __restrict__ hw,
                                                    const float* __restrict__ dinv,
                                                    const int* __restrict__ offsets,
                                                    const int2* __restrict__ csr_ew,
                                                    u8* __restrict__ hout) {
    int w = threadIdx.x >> 6;
    int lane = threadIdx.x & 63;
    int i = blockIdx.x * 4 + w;
    if (i >= N_NODES) return;
    float di = dinv[i];
    const u8* base = hw + (size_t)lane * 2;
    unsigned int su = *(const unsigned short*)(base + (size_t)i * IN_F);
    f32x2 sv = fp8x2_f32_lo(su);
    float s = di * di;
    float a0 = s * sv.x, a1 = s * sv.y;
    int t = offsets[i], end = offsets[i + 1];
    for (; t + 8 <= end; t += 8) {
        int2 e[8];
        unsigned int v[8];
        #pragma unroll
        for (int u = 0; u < 8; ++u) e[u] = csr_ew[t + u];
        #pragma unroll
        for (int u = 0; u < 8; ++u)
            v[u] = *(const unsigned short*)(base + (size_t)e[u].x * IN_F);
        #pragma unroll
        for (int u = 0; u < 8; ++u) {
            float wq = __int_as_float(e[u].y);
            f32x2 f = fp8x2_f32_lo(v[u]);
            a0 += wq * f.x; a1 += wq * f.y;
        }
    }
    for (; t < end; ++t) {
        int2 e0 = csr_ew[t];
        unsigned int v0 = *(const unsigned short*)(base + (size_t)e0.x * IN_F);
        float wq = __int_as_float(e0.y);
        f32x2 f = fp8x2_f32_lo(v0);
        a0 += wq * f.x; a1 += wq * f.y;
    }
    unsigned int o = f32_fp8x2_lo(a0, a1, 0u);
    *(unsigned short*)(hout + (size_t)i * IN_F + lane * 2) = (unsigned short)(o & 0xffff);
}

// ------------------------------------------------------------------
// GCN aggregation, 256-ch fp8, + relu. wave per node, lane = 4 channels.
// ------------------------------------------------------------------
__global__ __launch_bounds__(256) void aggregate256(const u8* __restrict__ hw,
                                                    const float* __restrict__ dinv,
                                                    const int* __restrict__ offsets,
                                                    const int2* __restrict__ csr_ew,
                                                    u8* __restrict__ hout) {
    int w = threadIdx.x >> 6;
    int lane = threadIdx.x & 63;
    int i = blockIdx.x * 4 + w;
    if (i >= N_NODES) return;
    float di = dinv[i];
    const u8* base = hw + (size_t)lane * 4;
    unsigned int su = *(const unsigned int*)(base + (size_t)i * H_F);
    f32x2 slo = fp8x2_f32_lo(su), shi = fp8x2_f32_hi(su);
    float s = di * di;
    float a0 = s * slo.x, a1 = s * slo.y, a2 = s * shi.x, a3 = s * shi.y;
    int t = offsets[i], end = offsets[i + 1];
    for (; t + 8 <= end; t += 8) {
        int2 e[8];
        unsigned int v[8];
        #pragma unroll
        for (int u = 0; u < 8; ++u) e[u] = csr_ew[t + u];
        #pragma unroll
        for (int u = 0; u < 8; ++u)
            v[u] = *(const unsigned int*)(base + (size_t)e[u].x * H_F);
        #pragma unroll
        for (int u = 0; u < 8; ++u) {
            float wq = __int_as_float(e[u].y);
            f32x2 lo = fp8x2_f32_lo(v[u]), hi = fp8x2_f32_hi(v[u]);
            a0 += wq * lo.x; a1 += wq * lo.y;
            a2 += wq * hi.x; a3 += wq * hi.y;
        }
    }
    for (; t < end; ++t) {
        int2 e0 = csr_ew[t];
        unsigned int v0 = *(const unsigned int*)(base + (size_t)e0.x * H_F);
        float wq = __int_as_float(e0.y);
        f32x2 lo = fp8x2_f32_lo(v0), hi = fp8x2_f32_hi(v0);
        a0 += wq * lo.x; a1 += wq * lo.y;
        a2 += wq * hi.x; a3 += wq * hi.y;
    }
    unsigned int o = f32_fp8x2_lo(fmaxf(a0, 0.f), fmaxf(a1, 0.f), 0u);
    o = f32_fp8x2_hi(fmaxf(a2, 0.f), fmaxf(a3, 0.f), o);
    *(unsigned int*)(hout + (size_t)i * H_F + lane * 4) = o;
}

// ------------------------------------------------------------------
// Pool: (graph, node-chunk) blocks, fp32 atomic partial sums. fp8 input.
// ------------------------------------------------------------------
__global__ __launch_bounds__(256) void pool_part(const u8* __restrict__ h,
                                                 const int* __restrict__ gstart,
                                                 float* __restrict__ pooled) {
    int g = blockIdx.x;
    int s = gstart[g] + blockIdx.y * POOL_CHUNK;
    int e = min(gstart[g + 1], s + POOL_CHUNK);
    if (s >= e) return;
    int c = threadIdx.x;
    float sum = 0.f;
    for (int i = s; i < e; ++i) {
        f32x2 f = fp8x2_f32_lo((unsigned int)h[(size_t)i * H_F + c]);
        sum += f.x;
    }
    atomicAdd(&pooled[g * H_F + c], sum);
}

// ------------------------------------------------------------------
// Fused MLP head (all fp32)
// ------------------------------------------------------------------
__global__ __launch_bounds__(256) void mlp_head_kernel(const float* __restrict__ pooled,
                                                       const int* __restrict__ gstart,
                                                       const float* __restrict__ Wm1,
                                                       const float* __restrict__ bm1,
                                                       const float* __restrict__ Wm2,
                                                       const float* __restrict__ bm2,
                                                       float* __restrict__ out) {
    __shared__ float p[H_F];
    __shared__ float h[H_F];
    __shared__ float lastv[OUT_F];
    __shared__ float stats[2];
    int g = blockIdx.x, j = threadIdx.x;
    int cnt = gstart[g + 1] - gstart[g];
    p[j] = pooled[g * H_F + j] / (float)max(cnt, 1);
    __syncthreads();
    float acc = bm1[j];
    for (int k = 0; k < H_F; ++k) acc += p[k] * Wm1[k * H_F + j];
    h[j] = fmaxf(acc, 0.f);
    __syncthreads();
    if (j < OUT_F) {
        float a = bm2[j];
        for (int k = 0; k < H_F; ++k) a += h[k] * Wm2[k * OUT_F + j];
        lastv[j] = a;
    }
    __syncthreads();
    if (j == 0) {
        float m = -1e30f;
        for (int o = 0; o < OUT_F; ++o) m = fmaxf(m, lastv[o]);
        float s = 0.f;
        for (int o = 0; o < OUT_F; ++o) s += expf(lastv[o] - m);
        stats[0] = m; stats[1] = logf(s);
    }
    __syncthreads();
    if (j < OUT_F) {
        float v = lastv[j];
        out[g * OUT_F + j] = v - stats[0] - stats[1];
        out[(size_t)N_G * OUT_F + g * OUT_F + j] = 1.f / (1.f + expf(-v));
        out[(size_t)2 * N_G * OUT_F + g * OUT_F + j] = v;
    }
}

// ------------------------------------------------------------------
extern "C" void kernel_launch(void* const* d_in, const int* in_sizes, int n_in,
                              void* d_out, int out_size, void* d_ws, size_t ws_size,
                              hipStream_t stream) {
    const float* x   = (const float*)d_in[0];
    const int* edge_index = (const int*)d_in[1];
    const int* batch = (const int*)d_in[3];
    const float* W0  = (const float*)d_in[4];
    const float* W1  = (const float*)d_in[5];
    const float* W2  = (const float*)d_in[6];
    const float* Wm1 = (const float*)d_in[7];
    const float* bm1 = (const float*)d_in[8];
    const float* Wm2 = (const float*)d_in[9];
    const float* bm2 = (const float*)d_in[10];
    float* out = (float*)d_out;

    char* ws = (char*)d_ws;
    size_t off = 0;
    auto alloc = [&](size_t bytes) -> void* {
        void* p = ws + off; off += (bytes + 255) & ~(size_t)255; return p;
    };
    u8* xb       = (u8*)alloc((size_t)N_PAD * IN_F);
    u8* bufA     = (u8*)alloc((size_t)N_PAD * H_F);
    u8* bufB     = (u8*)alloc((size_t)N_PAD * H_F);
    u8* t0       = (u8*)alloc((size_t)N_PAD * IN_F);
    u8* W0t      = (u8*)alloc((size_t)H_F * IN_F);
    u8* W1t      = (u8*)alloc((size_t)H_F * H_F);
    u8* W2t      = (u8*)alloc((size_t)H_F * H_F);
    float* dinv    = (float*)alloc((size_t)N_NODES * 4);
    int*   counts  = (int*)alloc((size_t)N_NODES * 4);
    int*   offsets = (int*)alloc((size_t)(N_NODES + 1) * 4);
    int*   cursor  = (int*)alloc((size_t)N_NODES * 4);
    int2*  csr_ew  = (int2*)alloc((size_t)N_EDGES * 8);
    int*   csum    = (int*)alloc((size_t)256 * 4);
    int*   gstart  = (int*)alloc((size_t)(N_G + 1) * 4);
    float* pooled  = (float*)alloc((size_t)N_G * H_F * 4);

    const int* row = edge_index;
    const int* col = edge_index + N_EDGES;

    hipMemsetAsync(counts, 0, (size_t)N_NODES * 4, stream);
    hipMemsetAsync(pooled, 0, (size_t)N_G * H_F * 4, stream);

    prep_kernel<<<PREP_GS, 256, 0, stream>>>(col, counts, x, xb,
                                             W0, W0t, W1, W1t, W2, W2t,
                                             batch, gstart);
    chunk_reduce<<<NCHUNKS, 256, 0, stream>>>(counts, csum, N_NODES);
    scan_dinv_kernel<<<NCHUNKS, 256, 0, stream>>>(counts, csum, offsets, dinv,
                                                  cursor, N_NODES);
    fill_csr_kernel<<<(N_EDGES + 255) / 256, 256, 0, stream>>>(row, col, offsets, cursor,
                                                               dinv, csr_ew, N_EDGES);

    dim3 gg(N_PAD / 128, H_F / 128);
    int agg_blocks = (N_NODES + 3) / 4;
    // layer 0: aggregate-first (linear ops commute), relu in GEMM epilogue
    aggregate128<<<agg_blocks, 256, 0, stream>>>(xb, dinv, offsets, csr_ew, t0);
    gemm_fp8<IN_F, true><<<gg, 256, 0, stream>>>(t0, W0t, bufA);
    // layer 1
    gemm_fp8<H_F, false><<<gg, 256, 0, stream>>>(bufA, W1t, bufB);
    aggregate256<<<agg_blocks, 256, 0, stream>>>(bufB, dinv, offsets, csr_ew, bufA);
    // layer 2
    gemm_fp8<H_F, false><<<gg, 256, 0, stream>>>(bufA, W2t, bufB);
    aggregate256<<<agg_blocks, 256, 0, stream>>>(bufB, dinv, offsets, csr_ew, bufA);

    dim3 pg(N_G, POOL_MAXCHUNKS);
    pool_part<<<pg, 256, 0, stream>>>(bufA, gstart, pooled);
    mlp_head_kernel<<<N_G, 256, 0, stream>>>(pooled, gstart, Wm1, bm1, Wm2, bm2, out);
}

// Round 9
// 377.639 us; speedup vs baseline: 2.8266x; 1.0057x over previous
//
#include <hip/hip_runtime.h>
#include <math.h>

#define N_NODES 50000
#define N_PAD   50048          // padded to multiple of 128 for GEMM tiles
#define N_EDGES 800000
#define IN_F 128
#define H_F 256
#define OUT_F 10
#define N_G 128
#define POOL_CHUNK 128
#define POOL_MAXCHUNKS 16
#define NCHUNKS 196            // ceil(N_NODES/256)

typedef __attribute__((ext_vector_type(4))) float f32x4;
typedef __attribute__((ext_vector_type(2))) float f32x2;
typedef unsigned char u8;

// ---- fp8 e4m3 (OCP) helpers: HW packed converts (imm word-select) ----
__device__ inline f32x2 fp8x2_f32_lo(unsigned int v) {
    return __builtin_amdgcn_cvt_pk_f32_fp8(v, false);
}
__device__ inline f32x2 fp8x2_f32_hi(unsigned int v) {
    return __builtin_amdgcn_cvt_pk_f32_fp8(v, true);
}
__device__ inline unsigned int f32_fp8x2_lo(float a, float b, unsigned int old) {
    return __builtin_amdgcn_cvt_pk_fp8_f32(a, b, old, false);
}
__device__ inline unsigned int f32_fp8x2_hi(float a, float b, unsigned int old) {
    return __builtin_amdgcn_cvt_pk_fp8_f32(a, b, old, true);
}
__device__ inline u8 f32_fp8(float a) {
    return (u8)(f32_fp8x2_lo(a, a, 0u) & 0xff);
}
// ---- bf16 helpers (packed CSR weight) ----
__device__ inline ushort f2bf(float x) {
    union { float f; unsigned int u; } v; v.f = x;
    unsigned int r = v.u + 0x7fff + ((v.u >> 16) & 1);
    return (ushort)(r >> 16);
}
__device__ inline float bf2f(ushort u) {
    union { unsigned int u; float f; } v; v.u = ((unsigned int)u) << 16; return v.f;
}

// async global->LDS, 16 B per lane; lds dest = wave-uniform base + lane*16
__device__ inline void gl2lds16(const void* g, void* l) {
    __builtin_amdgcn_global_load_lds(
        (const __attribute__((address_space(1))) unsigned int*)g,
        (__attribute__((address_space(3))) unsigned int*)l,
        16, 0, 0);
}

// ------------------------------------------------------------------
// Mega-fused prep (block roles by blockIdx range)
// ------------------------------------------------------------------
#define PREP_CE   3125
#define PREP_CV   (PREP_CE + 6250)
#define PREP_T0   (PREP_CV + 128)
#define PREP_T1   (PREP_T0 + 256)
#define PREP_T2   (PREP_T1 + 256)
#define PREP_GS   (PREP_T2 + NCHUNKS)

__global__ __launch_bounds__(256) void prep_kernel(
    const int* __restrict__ col, int* __restrict__ counts,
    const float* __restrict__ x, u8* __restrict__ xb,
    const float* __restrict__ W0, u8* __restrict__ W0t,
    const float* __restrict__ W1, u8* __restrict__ W1t,
    const float* __restrict__ W2, u8* __restrict__ W2t,
    const int* __restrict__ batch, int* __restrict__ gstart) {
    int b = blockIdx.x;
    int tid = threadIdx.x;
    if (b < PREP_CE) {
        int e = b * 256 + tid;
        if (e < N_EDGES) atomicAdd(&counts[col[e]], 1);
    } else if (b < PREP_CV) {
        int i = (b - PREP_CE) * 256 + tid;      // < 1,600,000 exactly
        float4 v = *(const float4*)(x + (size_t)i * 4);
        unsigned int p = f32_fp8x2_lo(v.x, v.y, 0u);
        p = f32_fp8x2_hi(v.z, v.w, p);
        *(unsigned int*)(xb + (size_t)i * 4) = p;
    } else if (b < PREP_T0) {
        int idx = (b - PREP_CV) * 256 + tid;    // < 32768
        int k = idx >> 8, nn = idx & 255;       // K=128, Nc=256
        W0t[nn * IN_F + k] = f32_fp8(W0[idx]);
    } else if (b < PREP_T1) {
        int idx = (b - PREP_T0) * 256 + tid;    // < 65536
        int k = idx >> 8, nn = idx & 255;
        W1t[nn * H_F + k] = f32_fp8(W1[idx]);
    } else if (b < PREP_T2) {
        int idx = (b - PREP_T1) * 256 + tid;
        int k = idx >> 8, nn = idx & 255;
        W2t[nn * H_F + k] = f32_fp8(W2[idx]);
    } else {
        int i = (b - PREP_T2) * 256 + tid;
        if (i >= N_NODES) return;
        int bb = batch[i];
        if (i == 0) {
            for (int g = 0; g <= bb; ++g) gstart[g] = 0;
        } else {
            int p = batch[i - 1];
            if (p != bb) { for (int g = p + 1; g <= bb; ++g) gstart[g] = i; }
        }
        if (i == N_NODES - 1) {
            for (int g = bb + 1; g <= N_G; ++g) gstart[g] = N_NODES;
        }
    }
}

// ------------------------------------------------------------------
// per-chunk sums of counts (196 blocks)
// ------------------------------------------------------------------
__global__ __launch_bounds__(256) void chunk_reduce(const int* __restrict__ counts,
                                                    int* __restrict__ csum, int n) {
    int i = blockIdx.x * 256 + threadIdx.x;
    int v = (i < n) ? counts[i] : 0;
    #pragma unroll
    for (int off = 32; off; off >>= 1) v += __shfl_down(v, off);
    __shared__ int ws[4];
    if ((threadIdx.x & 63) == 0) ws[threadIdx.x >> 6] = v;
    __syncthreads();
    if (threadIdx.x == 0) csum[blockIdx.x] = ws[0] + ws[1] + ws[2] + ws[3];
}

// ------------------------------------------------------------------
// scan + dinv + cursor-zero, fully parallel (196 blocks)
// ------------------------------------------------------------------
__global__ __launch_bounds__(256) void scan_dinv_kernel(const int* __restrict__ counts,
                                                        const int* __restrict__ csum,
                                                        int* __restrict__ offsets,
                                                        float* __restrict__ dinv,
                                                        int* __restrict__ cursor, int n) {
    int tid = threadIdx.x;
    int lane = tid & 63, wid = tid >> 6;
    int cv = (tid < NCHUNKS) ? csum[tid] : 0;
    int xc = cv;
    #pragma unroll
    for (int off = 1; off < 64; off <<= 1) {
        int t = __shfl_up(xc, off);
        if (lane >= off) xc += t;
    }
    __shared__ int cw[4], cpre[4];
    __shared__ int cexcl[256];
    if (lane == 63) cw[wid] = xc;
    __syncthreads();
    if (tid == 0) { int s = 0; for (int k = 0; k < 4; ++k) { cpre[k] = s; s += cw[k]; } }
    __syncthreads();
    cexcl[tid] = cpre[wid] + xc - cv;
    __syncthreads();
    int base = cexcl[blockIdx.x];
    int i = blockIdx.x * 256 + tid;
    int v = (i < n) ? counts[i] : 0;
    int x = v;
    #pragma unroll
    for (int off = 1; off < 64; off <<= 1) {
        int t = __shfl_up(x, off);
        if (lane >= off) x += t;
    }
    __shared__ int wsum[4], wpre[4];
    if (lane == 63) wsum[wid] = x;
    __syncthreads();
    if (tid == 0) { int s = 0; for (int k = 0; k < 4; ++k) { wpre[k] = s; s += wsum[k]; } }
    __syncthreads();
    if (i < n) {
        offsets[i] = base + wpre[wid] + x - v;   // exclusive
        dinv[i] = rsqrtf((float)(v + 1));
        cursor[i] = 0;
    }
    if (blockIdx.x == 0 && tid == 0) offsets[n] = N_EDGES;
}

// Packed CSR: entry = src (16 bits, N_NODES<65536) | bf16 weight << 16.
// weight = dinv[dst]*dinv[src]
__global__ void fill_csr_kernel(const int* __restrict__ row, const int* __restrict__ col,
                                const int* __restrict__ offsets, int* __restrict__ cursor,
                                const float* __restrict__ dinv,
                                unsigned int* __restrict__ csr_ew, int E) {
    int e = blockIdx.x * blockDim.x + threadIdx.x;
    if (e < E) {
        int c = col[e];
        int r = row[e];
        int p = atomicAdd(&cursor[c], 1);
        float w = dinv[c] * dinv[r];
        csr_ew[offsets[c] + p] = (unsigned int)r | ((unsigned int)f2bf(w) << 16);
    }
}

// ------------------------------------------------------------------
// fp8 MFMA GEMM: C[N_PAD x 256] = A[N_PAD x K] @ Bt^T   (Bt is [256][K], fp8)
// 128x128 tile / block (4 waves 2x2), BK=128: four 4 KB k-planes per operand
// per stage ([128 rows][32 k-bytes] each), async global_load_lds staging.
// K=128 -> single stage (1 barrier); K=256 -> 2 stages (3 barriers).
// LDS 32 KB/block -> ~5 blocks/CU; all 782 blocks co-resident.
// ------------------------------------------------------------------
template <int K, bool RELU>
__global__ __launch_bounds__(256) void gemm_fp8(const u8* __restrict__ A,
                                                const u8* __restrict__ Bt,
                                                u8* __restrict__ C) {
    __shared__ u8 As[4 * 4096];
    __shared__ u8 Bs[4 * 4096];
    int tid = threadIdx.x;
    int lane = tid & 63;
    int w = tid >> 6;
    int wm = w & 1, wn = w >> 1;
    int l16 = lane & 15, quad = lane >> 4;
    int row0 = blockIdx.x * 128;
    int col0 = blockIdx.y * 128;
    f32x4 acc[4][4] = {};

    int sr = tid >> 1;             // staging row 0..127
    int sh = (tid & 1) * 16;       // half-plane-row byte offset
    const u8* ga = A + (size_t)(row0 + sr) * K + sh;
    const u8* gb = Bt + (size_t)(col0 + sr) * K + sh;

    #pragma unroll
    for (int k0 = 0; k0 < K; k0 += 128) {
        if (k0) __syncthreads();
        #pragma unroll
        for (int q = 0; q < 4; ++q) {   // k-plane within stage
            gl2lds16(ga + k0 + q * 32, As + q * 4096 + w * 1024);
            gl2lds16(gb + k0 + q * 32, Bs + q * 4096 + w * 1024);
        }
        __syncthreads();
        #pragma unroll
        for (int h = 0; h < 4; ++h) {
            long af[4], bfr[4];
            #pragma unroll
            for (int i = 0; i < 4; ++i)
                af[i] = *(const long*)&As[h * 4096 + (wm * 64 + i * 16 + l16) * 32 + quad * 8];
            #pragma unroll
            for (int j = 0; j < 4; ++j)
                bfr[j] = *(const long*)&Bs[h * 4096 + (wn * 64 + j * 16 + l16) * 32 + quad * 8];
            #pragma unroll
            for (int i = 0; i < 4; ++i)
                #pragma unroll
                for (int j = 0; j < 4; ++j)
                    acc[i][j] = __builtin_amdgcn_mfma_f32_16x16x32_fp8_fp8(af[i], bfr[j], acc[i][j], 0, 0, 0);
        }
    }
    // epilogue: C/D layout col=lane&15, row=quad*4+reg (dtype-independent)
    #pragma unroll
    for (int i = 0; i < 4; ++i) {
        int rowb = row0 + wm * 64 + i * 16 + quad * 4;
        #pragma unroll
        for (int r = 0; r < 4; ++r) {
            int grow = rowb + r;
            #pragma unroll
            for (int j = 0; j < 4; ++j) {
                int gcol = col0 + wn * 64 + j * 16 + l16;
                float v = acc[i][j][r];
                if (RELU) v = fmaxf(v, 0.f);
                C[(size_t)grow * H_F + gcol] = f32_fp8(v);
            }
        }
    }
}

// ------------------------------------------------------------------
// GCN aggregation, 128-ch fp8 (layer-0, pre-GEMM), NO relu.
// wave per node, lane = 2 channels (2 B load), edge loop unrolled x8.
// ------------------------------------------------------------------
__global__ __launch_bounds__(256) void aggregate128(const u8* __restrict__ hw,
                                                    const float* __restrict__ dinv,
                                                    const int* __restrict__ offsets,
                                                    const unsigned int* __restrict__ csr_ew,
                                                    u8* __restrict__ hout) {
    int w = threadIdx.x >> 6;
    int lane = threadIdx.x & 63;
    int i = blockIdx.x * 4 + w;
    if (i >= N_NODES) return;
    float di = dinv[i];
    const u8* base = hw + (size_t)lane * 2;
    unsigned int su = *(const unsigned short*)(base + (size_t)i * IN_F);
    f32x2 sv = fp8x2_f32_lo(su);
    float s = di * di;
    float a0 = s * sv.x, a1 = s * sv.y;
    int t = offsets[i], end = offsets[i + 1];
    for (; t + 8 <= end; t += 8) {
        unsigned int e[8];
        unsigned int v[8];
        #pragma unroll
        for (int u = 0; u < 8; ++u) e[u] = csr_ew[t + u];
        #pragma unroll
        for (int u = 0; u < 8; ++u)
            v[u] = *(const unsigned short*)(base + (size_t)(e[u] & 0xffff) * IN_F);
        #pragma unroll
        for (int u = 0; u < 8; ++u) {
            float wq = bf2f((ushort)(e[u] >> 16));
            f32x2 f = fp8x2_f32_lo(v[u]);
            a0 += wq * f.x; a1 += wq * f.y;
        }
    }
    for (; t < end; ++t) {
        unsigned int e0 = csr_ew[t];
        unsigned int v0 = *(const unsigned short*)(base + (size_t)(e0 & 0xffff) * IN_F);
        float wq = bf2f((ushort)(e0 >> 16));
        f32x2 f = fp8x2_f32_lo(v0);
        a0 += wq * f.x; a1 += wq * f.y;
    }
    unsigned int o = f32_fp8x2_lo(a0, a1, 0u);
    *(unsigned short*)(hout + (size_t)i * IN_F + lane * 2) = (unsigned short)(o & 0xffff);
}

// ------------------------------------------------------------------
// GCN aggregation, 256-ch fp8, + relu. wave per node, lane = 4 channels.
// ------------------------------------------------------------------
__global__ __launch_bounds__(256) void aggregate256(const u8* __restrict__ hw,
                                                    const float* __restrict__ dinv,
                                                    const int* __restrict__ offsets,
                                                    const unsigned int* __restrict__ csr_ew,
                                                    u8* __restrict__ hout) {
    int w = threadIdx.x >> 6;
    int lane = threadIdx.x & 63;
    int i = blockIdx.x * 4 + w;
    if (i >= N_NODES) return;
    float di = dinv[i];
    const u8* base = hw + (size_t)lane * 4;
    unsigned int su = *(const unsigned int*)(base + (size_t)i * H_F);
    f32x2 slo = fp8x2_f32_lo(su), shi = fp8x2_f32_hi(su);
    float s = di * di;
    float a0 = s * slo.x, a1 = s * slo.y, a2 = s * shi.x, a3 = s * shi.y;
    int t = offsets[i], end = offsets[i + 1];
    for (; t + 8 <= end; t += 8) {
        unsigned int e[8];
        unsigned int v[8];
        #pragma unroll
        for (int u = 0; u < 8; ++u) e[u] = csr_ew[t + u];
        #pragma unroll
        for (int u = 0; u < 8; ++u)
            v[u] = *(const unsigned int*)(base + (size_t)(e[u] & 0xffff) * H_F);
        #pragma unroll
        for (int u = 0; u < 8; ++u) {
            float wq = bf2f((ushort)(e[u] >> 16));
            f32x2 lo = fp8x2_f32_lo(v[u]), hi = fp8x2_f32_hi(v[u]);
            a0 += wq * lo.x; a1 += wq * lo.y;
            a2 += wq * hi.x; a3 += wq * hi.y;
        }
    }
    for (; t < end; ++t) {
        unsigned int e0 = csr_ew[t];
        unsigned int v0 = *(const unsigned int*)(base + (size_t)(e0 & 0xffff) * H_F);
        float wq = bf2f((ushort)(e0 >> 16));
        f32x2 lo = fp8x2_f32_lo(v0), hi = fp8x2_f32_hi(v0);
        a0 += wq * lo.x; a1 += wq * lo.y;
        a2 += wq * hi.x; a3 += wq * hi.y;
    }
    unsigned int o = f32_fp8x2_lo(fmaxf(a0, 0.f), fmaxf(a1, 0.f), 0u);
    o = f32_fp8x2_hi(fmaxf(a2, 0.f), fmaxf(a3, 0.f), o);
    *(unsigned int*)(hout + (size_t)i * H_F + lane * 4) = o;
}

// ------------------------------------------------------------------
// Pool: (graph, node-chunk) blocks, fp32 atomic partial sums. fp8 input.
// ------------------------------------------------------------------
__global__ __launch_bounds__(256) void pool_part(const u8* __restrict__ h,
                                                 const int* __restrict__ gstart,
                                                 float* __restrict__ pooled) {
    int g = blockIdx.x;
    int s = gstart[g] + blockIdx.y * POOL_CHUNK;
    int e = min(gstart[g + 1], s + POOL_CHUNK);
    if (s >= e) return;
    int c = threadIdx.x;
    float sum = 0.f;
    for (int i = s; i < e; ++i) {
        f32x2 f = fp8x2_f32_lo((unsigned int)h[(size_t)i * H_F + c]);
        sum += f.x;
    }
    atomicAdd(&pooled[g * H_F + c], sum);
}

// ------------------------------------------------------------------
// Fused MLP head (all fp32)
// ------------------------------------------------------------------
__global__ __launch_bounds__(256) void mlp_head_kernel(const float* __restrict__ pooled,
                                                       const int* __restrict__ gstart,
                                                       const float* __restrict__ Wm1,
                                                       const float* __restrict__ bm1,
                                                       const float* __restrict__ Wm2,
                                                       const float* __restrict__ bm2,
                                                       float* __restrict__ out) {
    __shared__ float p[H_F];
    __shared__ float h[H_F];
    __shared__ float lastv[OUT_F];
    __shared__ float stats[2];
    int g = blockIdx.x, j = threadIdx.x;
    int cnt = gstart[g + 1] - gstart[g];
    p[j] = pooled[g * H_F + j] / (float)max(cnt, 1);
    __syncthreads();
    float acc = bm1[j];
    for (int k = 0; k < H_F; ++k) acc += p[k] * Wm1[k * H_F + j];
    h[j] = fmaxf(acc, 0.f);
    __syncthreads();
    if (j < OUT_F) {
        float a = bm2[j];
        for (int k = 0; k < H_F; ++k) a += h[k] * Wm2[k * OUT_F + j];
        lastv[j] = a;
    }
    __syncthreads();
    if (j == 0) {
        float m = -1e30f;
        for (int o = 0; o < OUT_F; ++o) m = fmaxf(m, lastv[o]);
        float s = 0.f;
        for (int o = 0; o < OUT_F; ++o) s += expf(lastv[o] - m);
        stats[0] = m; stats[1] = logf(s);
    }
    __syncthreads();
    if (j < OUT_F) {
        float v = lastv[j];
        out[g * OUT_F + j] = v - stats[0] - stats[1];
        out[(size_t)N_G * OUT_F + g * OUT_F + j] = 1.f / (1.f + expf(-v));
        out[(size_t)2 * N_G * OUT_F + g * OUT_F + j] = v;
    }
}

// ------------------------------------------------------------------
extern "C" void kernel_launch(void* const* d_in, const int* in_sizes, int n_in,
                              void* d_out, int out_size, void* d_ws, size_t ws_size,
                              hipStream_t stream) {
    const float* x   = (const float*)d_in[0];
    const int* edge_index = (const int*)d_in[1];
    const int* batch = (const int*)d_in[3];
    const float* W0  = (const float*)d_in[4];
    const float* W1  = (const float*)d_in[5];
    const float* W2  = (const float*)d_in[6];
    const float* Wm1 = (const float*)d_in[7];
    const float* bm1 = (const float*)d_in[8];
    const float* Wm2 = (const float*)d_in[9];
    const float* bm2 = (const float*)d_in[10];
    float* out = (float*)d_out;

    char* ws = (char*)d_ws;
    size_t off = 0;
    auto alloc = [&](size_t bytes) -> void* {
        void* p = ws + off; off += (bytes + 255) & ~(size_t)255; return p;
    };
    u8* xb       = (u8*)alloc((size_t)N_PAD * IN_F);
    u8* bufA     = (u8*)alloc((size_t)N_PAD * H_F);
    u8* bufB     = (u8*)alloc((size_t)N_PAD * H_F);
    u8* t0       = (u8*)alloc((size_t)N_PAD * IN_F);
    u8* W0t      = (u8*)alloc((size_t)H_F * IN_F);
    u8* W1t      = (u8*)alloc((size_t)H_F * H_F);
    u8* W2t      = (u8*)alloc((size_t)H_F * H_F);
    float* dinv    = (float*)alloc((size_t)N_NODES * 4);
    int*   counts  = (int*)alloc((size_t)N_NODES * 4);
    int*   offsets = (int*)alloc((size_t)(N_NODES + 1) * 4);
    int*   cursor  = (int*)alloc((size_t)N_NODES * 4);
    unsigned int* csr_ew = (unsigned int*)alloc((size_t)N_EDGES * 4);
    int*   csum    = (int*)alloc((size_t)256 * 4);
    int*   gstart  = (int*)alloc((size_t)(N_G + 1) * 4);
    float* pooled  = (float*)alloc((size_t)N_G * H_F * 4);

    const int* row = edge_index;
    const int* col = edge_index + N_EDGES;

    hipMemsetAsync(counts, 0, (size_t)N_NODES * 4, stream);
    hipMemsetAsync(pooled, 0, (size_t)N_G * H_F * 4, stream);

    prep_kernel<<<PREP_GS, 256, 0, stream>>>(col, counts, x, xb,
                                             W0, W0t, W1, W1t, W2, W2t,
                                             batch, gstart);
    chunk_reduce<<<NCHUNKS, 256, 0, stream>>>(counts, csum, N_NODES);
    scan_dinv_kernel<<<NCHUNKS, 256, 0, stream>>>(counts, csum, offsets, dinv,
                                                  cursor, N_NODES);
    fill_csr_kernel<<<(N_EDGES + 255) / 256, 256, 0, stream>>>(row, col, offsets, cursor,
                                                               dinv, csr_ew, N_EDGES);

    dim3 gg(N_PAD / 128, H_F / 128);
    int agg_blocks = (N_NODES + 3) / 4;
    // layer 0: aggregate-first (linear ops commute), relu in GEMM epilogue
    aggregate128<<<agg_blocks, 256, 0, stream>>>(xb, dinv, offsets, csr_ew, t0);
    gemm_fp8<IN_F, true><<<gg, 256, 0, stream>>>(t0, W0t, bufA);
    // layer 1
    gemm_fp8<H_F, false><<<gg, 256, 0, stream>>>(bufA, W1t, bufB);
    aggregate256<<<agg_blocks, 256, 0, stream>>>(bufB, dinv, offsets, csr_ew, bufA);
    // layer 2
    gemm_fp8<H_F, false><<<gg, 256, 0, stream>>>(bufA, W2t, bufB);
    aggregate256<<<agg_blocks, 256, 0, stream>>>(bufB, dinv, offsets, csr_ew, bufA);

    dim3 pg(N_G, POOL_MAXCHUNKS);
    pool_part<<<pg, 256, 0, stream>>>(bufA, gstart, pooled);
    mlp_head_kernel<<<N_G, 256, 0, stream>>>(pooled, gstart, Wm1, bm1, Wm2, bm2, out);
}